// Round 9
// baseline (216.545 us; speedup 1.0000x reference)
//
#include <hip/hip_runtime.h>

// BayesianMambaBlock on MI355X (gfx950).
// LN -> fused (in|gate) GEMM (bf16 out) -> conv+silu (bf16) -> S GEMM (fused u, bf16 out) ->
// abcd GEMM split-K4 + combine (dec/B/C) -> chunked scan (phase3 fused gate) -> out GEMM (+resid, f32).
// gemm_bt: 256 thr / 4 waves, 64x64 wave tile (0.5 LDS-reads per MFMA), 3 LDS buffers (48KB, 3 blocks/CU),
// depth-2 counted vmcnt(4) pipeline, chunk-XOR LDS swizzle, XCD-aware block swizzle.

typedef unsigned short u16;
using short8 = __attribute__((ext_vector_type(8))) short;
using f32x4  = __attribute__((ext_vector_type(4))) float;

#define BATCH 2
#define SEQ   2048
#define DM    768
#define DI    1536
#define NIG   (2*DI)        // fused in+gate width 3072
#define NST   16
#define LCH   64
#define NCH   32
#define NTOK  (BATCH*SEQ)   // 4096

__device__ __forceinline__ u16 f2b(float x) {
  unsigned u = __float_as_uint(x);
  u += 0x7FFFu + ((u >> 16) & 1u);   // round-to-nearest-even bf16
  return (u16)(u >> 16);
}
__device__ __forceinline__ float b2f(u16 v) { return __uint_as_float((unsigned)v << 16); }
__device__ __forceinline__ float sigmoidf_(float x) { return 1.f / (1.f + expf(-x)); }
__device__ __forceinline__ float siluf_(float x) { return x / (1.f + expf(-x)); }

// ---------------- f32 -> bf16 casts: two buffers in one launch ----------------
__global__ __launch_bounds__(256) void cast_two(const float* __restrict__ in1, u16* __restrict__ out1, int n1,
                                                const float* __restrict__ in2, u16* __restrict__ out2, int n2) {
  int i = blockIdx.x * 256 + threadIdx.x;
  if (i < n1) {
    float4 v = ((const float4*)in1)[i];
    ushort4 o; o.x = f2b(v.x); o.y = f2b(v.y); o.z = f2b(v.z); o.w = f2b(v.w);
    ((ushort4*)out1)[i] = o;
  } else if (i - n1 < n2) {
    int j = i - n1;
    float4 v = ((const float4*)in2)[j];
    ushort4 o; o.x = f2b(v.x); o.y = f2b(v.y); o.z = f2b(v.z); o.w = f2b(v.w);
    ((ushort4*)out2)[j] = o;
  }
}

// ---------------- concat W_in|W_gate -> bf16 [3072][768] + bias3072 ----------------
__global__ __launch_bounds__(256) void cast_ingate(const float* __restrict__ Wi, const float* __restrict__ Wg,
                                                   const float* __restrict__ bi, const float* __restrict__ bg,
                                                   u16* __restrict__ Wb, float* __restrict__ bias) {
  int i = blockIdx.x * 256 + threadIdx.x;   // < NIG*DM
  if (i >= NIG * DM) return;
  int r = i / DM, c = i % DM;
  Wb[i] = f2b(r < DI ? Wi[(size_t)r * DM + c] : Wg[(size_t)(r - DI) * DM + c]);
  if (i < NIG) bias[i] = (i < DI) ? bi[i] : bg[i - DI];
}

// ---------------- concat W_A/W_dt/W_B/W_C -> bf16 [64][DI] + bias64 ----------------
__global__ __launch_bounds__(256) void cast_wabcd(const float* __restrict__ WA, const float* __restrict__ Wdt,
                                                  const float* __restrict__ WB, const float* __restrict__ WC,
                                                  const float* __restrict__ bA, const float* __restrict__ bdt,
                                                  const float* __restrict__ bB, const float* __restrict__ bC,
                                                  u16* __restrict__ Wb, float* __restrict__ bias64) {
  int i = blockIdx.x * 256 + threadIdx.x;   // < 64*DI
  if (i >= 64 * DI) return;
  int r = i / DI, c = i % DI;
  const float* src = (r < 16) ? WA + (size_t)r * DI
                  : (r < 32) ? Wdt + (size_t)(r - 16) * DI
                  : (r < 48) ? WB + (size_t)(r - 32) * DI
                             : WC + (size_t)(r - 48) * DI;
  Wb[i] = f2b(src[c]);
  if (i < 64) bias64[i] = (i < 16) ? bA[i] : (i < 32) ? bdt[i - 16] : (i < 48) ? bB[i - 32] : bC[i - 48];
}

// ---------------- LayerNorm -> bf16 ----------------
__global__ __launch_bounds__(256) void ln_kernel(const float* __restrict__ x, const float* __restrict__ g,
                                                 const float* __restrict__ bb, u16* __restrict__ xn) {
  int m = blockIdx.x, tid = threadIdx.x;
  const float* xr = x + (size_t)m * DM;
  float v0 = xr[tid], v1 = xr[tid + 256], v2 = xr[tid + 512];
  float s  = v0 + v1 + v2;
  float s2 = fmaf(v0, v0, fmaf(v1, v1, v2 * v2));
  #pragma unroll
  for (int off = 32; off > 0; off >>= 1) { s += __shfl_down(s, off); s2 += __shfl_down(s2, off); }
  __shared__ float sh[8];
  int wave = tid >> 6, lane = tid & 63;
  if (lane == 0) { sh[wave] = s; sh[4 + wave] = s2; }
  __syncthreads();
  float S1 = sh[0] + sh[1] + sh[2] + sh[3];
  float S2 = sh[4] + sh[5] + sh[6] + sh[7];
  float mu = S1 * (1.f / DM);
  float var = S2 * (1.f / DM) - mu * mu;
  float rs = rsqrtf(var + 1e-5f);
  u16* o = xn + (size_t)m * DM;
  o[tid]       = f2b((v0 - mu) * rs * g[tid]       + bb[tid]);
  o[tid + 256] = f2b((v1 - mu) * rs * g[tid + 256] + bb[tid + 256]);
  o[tid + 512] = f2b((v2 - mu) * rs * g[tid + 512] + bb[tid + 512]);
}

// ---------------- bf16 MFMA NT-GEMM: acc = A[M][K] * B[N][K]^T + bias ----------------
// 256 threads, 4 waves, 128x128 block tile, 64x64 wave tile, BK=32.
// 3 LDS buffers, depth-2 pipeline: counted vmcnt(4) + raw s_barrier; tail 4->0.
// MODE 0: C f32 = acc + bias + aux(resid, f32)
// MODE 1: u-mode: uv = b2f(auxb) * sigmoid(acc+bias); Cb = bf16(uv)
// MODE 2: Cb = bf16(acc + bias)
__device__ __forceinline__ void gll16(const void* g, void* l) {
  __builtin_amdgcn_global_load_lds((const __attribute__((address_space(1))) void*)g,
                                   (__attribute__((address_space(3))) void*)l, 16, 0, 0);
}

template <int MODE>
__global__ __launch_bounds__(256) void gemm_bt(const u16* __restrict__ A, const u16* __restrict__ B,
                                               const float* __restrict__ bias, const float* __restrict__ aux,
                                               const u16* __restrict__ auxb,
                                               float* __restrict__ C, u16* __restrict__ Cb,
                                               int M, int N, int K) {
  __shared__ __align__(16) u16 As[3][128 * 32];
  __shared__ __align__(16) u16 Bs[3][128 * 32];
  const int tid = threadIdx.x, wave = tid >> 6, lane = tid & 63;

  // XCD-aware bijective swizzle (nwg % 8 == 0 for all our grids)
  const int nbx = gridDim.x, nwg = nbx * gridDim.y;
  const int orig = blockIdx.y * nbx + blockIdx.x;
  const int cpx = nwg >> 3;
  const int swz = (orig & 7) * cpx + (orig >> 3);
  const int m0 = (swz / nbx) * 128, n0 = (swz % nbx) * 128;

  const int wm = (wave >> 1) * 64, wn = (wave & 1) * 64;
  const int fr = lane & 15, fq = lane >> 4;
  f32x4 acc[4][4] = {};

  // staging: LDS chunk c (linear dest) holds global k-chunk (c&3)^((c>>3)&3) of row c>>2
  const int c0 = tid, c1 = tid + 256;   // 512 chunks of 16B cover 128x32
  const u16* Ag0 = A + (size_t)(m0 + (c0 >> 2)) * K + ((c0 & 3) ^ ((c0 >> 3) & 3)) * 8;
  const u16* Ag1 = A + (size_t)(m0 + (c1 >> 2)) * K + ((c1 & 3) ^ ((c1 >> 3) & 3)) * 8;
  const u16* Bg0 = B + (size_t)(n0 + (c0 >> 2)) * K + ((c0 & 3) ^ ((c0 >> 3) & 3)) * 8;
  const u16* Bg1 = B + (size_t)(n0 + (c1 >> 2)) * K + ((c1 & 3) ^ ((c1 >> 3) & 3)) * 8;
  const int lo0 = (wave * 64) * 8;          // wave-uniform LDS base; HW adds lane*16B
  const int lo1 = (256 + wave * 64) * 8;

  // swizzled ds_read offsets (u16 units), 2-way max per 8 bank-slots
  int offA[4], offB[4];
  #pragma unroll
  for (int i = 0; i < 4; ++i) {
    int ra = wm + i * 16 + fr;
    int rb = wn + i * 16 + fr;
    offA[i] = ra * 32 + (fq ^ ((ra >> 1) & 3)) * 8;
    offB[i] = rb * 32 + (fq ^ ((rb >> 1) & 3)) * 8;
  }

  const int nk = K >> 5;   // >= 24

#define STAGE_BT(tt, bb) { gll16(Ag0 + (tt) * 32, (u16*)As[bb] + lo0); \
                           gll16(Ag1 + (tt) * 32, (u16*)As[bb] + lo1); \
                           gll16(Bg0 + (tt) * 32, (u16*)Bs[bb] + lo0); \
                           gll16(Bg1 + (tt) * 32, (u16*)Bs[bb] + lo1); }
#define COMPUTE_BT(bb) { const u16* as_ = As[bb]; const u16* bs_ = Bs[bb]; \
    short8 av[4], bv[4]; \
    _Pragma("unroll") for (int i = 0; i < 4; ++i) av[i] = *(const short8*)(as_ + offA[i]); \
    _Pragma("unroll") for (int i = 0; i < 4; ++i) bv[i] = *(const short8*)(bs_ + offB[i]); \
    _Pragma("unroll") for (int mi = 0; mi < 4; ++mi) \
      _Pragma("unroll") for (int ni = 0; ni < 4; ++ni) \
        acc[mi][ni] = __builtin_amdgcn_mfma_f32_16x16x32_bf16(av[mi], bv[ni], acc[mi][ni], 0, 0, 0); }

  STAGE_BT(0, 0); STAGE_BT(1, 1);   // 8 loads in flight per wave
  int b0 = 0, b1 = 1, b2 = 2;

  for (int t = 0; t < nk - 2; ++t) {
    asm volatile("s_waitcnt vmcnt(4)" ::: "memory");   // tile t arrived; t+1 still in flight
    __builtin_amdgcn_s_barrier();
    STAGE_BT(t + 2, b2);            // b2 was read at iter t-1; all its readers passed this barrier
    COMPUTE_BT(b0);
    int tmp = b0; b0 = b1; b1 = b2; b2 = tmp;
  }
  asm volatile("s_waitcnt vmcnt(4)" ::: "memory");
  __builtin_amdgcn_s_barrier();
  COMPUTE_BT(b0);
  asm volatile("s_waitcnt vmcnt(0)" ::: "memory");
  __builtin_amdgcn_s_barrier();
  COMPUTE_BT(b1);
#undef STAGE_BT
#undef COMPUTE_BT

  #pragma unroll
  for (int ni = 0; ni < 4; ++ni) {
    int col = n0 + wn + ni * 16 + fr;
    float bv_ = bias[col];
    #pragma unroll
    for (int mi = 0; mi < 4; ++mi) {
      int row = m0 + wm + mi * 16 + fq * 4;
      #pragma unroll
      for (int j = 0; j < 4; ++j) {
        size_t off = (size_t)(row + j) * N + col;
        float z = acc[mi][ni][j] + bv_;
        if (MODE == 0) {
          C[off] = z + aux[off];
        } else if (MODE == 1) {
          Cb[off] = f2b(b2f(auxb[off]) * sigmoidf_(z));
        } else {
          Cb[off] = f2b(z);
        }
      }
    }
  }
}

// ---------------- abcd GEMM split-K: Zp[ks] = ub[M][Kq] * Wabcd[64][Kq]^T ----------------
// grid (M/64, 4); 256 threads, 64x64 tile, BK=64, double-buffered (__syncthreads).
__global__ __launch_bounds__(256) void gemm_abcd(const u16* __restrict__ A, const u16* __restrict__ B,
                                                 float* __restrict__ Zp, int M, int K) {
  __shared__ __align__(16) u16 As[2][64 * 64];
  __shared__ __align__(16) u16 Bs[2][64 * 64];
  const int tid = threadIdx.x, wave = tid >> 6, lane = tid & 63;
  const int m0 = blockIdx.x * 64;
  const int ks = blockIdx.y;
  const int Kq = K >> 2;            // 384
  const int kbase = ks * Kq;
  const int wm = wave * 16;
  const int fr = lane & 15, fq = lane >> 4;
  f32x4 acc[4] = {};

  // 512 chunks of 16B cover 64x64; chunk c: row=c>>3, LDS slot c&7 holds k-chunk (c&7)^(row&7)
  const int c0 = tid, c1 = tid + 256;
  const u16* Ag0 = A + (size_t)(m0 + (c0 >> 3)) * K + kbase + ((c0 & 7) ^ ((c0 >> 3) & 7)) * 8;
  const u16* Ag1 = A + (size_t)(m0 + (c1 >> 3)) * K + kbase + ((c1 & 7) ^ ((c1 >> 3) & 7)) * 8;
  const u16* Bg0 = B + (size_t)(c0 >> 3) * K + kbase + ((c0 & 7) ^ ((c0 >> 3) & 7)) * 8;
  const u16* Bg1 = B + (size_t)(c1 >> 3) * K + kbase + ((c1 & 7) ^ ((c1 >> 3) & 7)) * 8;
  const int lo0 = (wave * 64) * 8;
  const int lo1 = (256 + wave * 64) * 8;

  int offAv[2], offBv[2][4];
  {
    int r = wm + fr;
    #pragma unroll
    for (int kk = 0; kk < 2; ++kk) offAv[kk] = r * 64 + ((kk * 4 + fq) ^ (r & 7)) * 8;
    #pragma unroll
    for (int i = 0; i < 4; ++i) {
      int rb = i * 16 + fr;
      #pragma unroll
      for (int kk = 0; kk < 2; ++kk) offBv[kk][i] = rb * 64 + ((kk * 4 + fq) ^ (rb & 7)) * 8;
    }
  }

  const int nk = Kq >> 6;   // 6
  gll16(Ag0, (u16*)As[0] + lo0);
  gll16(Ag1, (u16*)As[0] + lo1);
  gll16(Bg0, (u16*)Bs[0] + lo0);
  gll16(Bg1, (u16*)Bs[0] + lo1);

  for (int t = 0; t < nk; ++t) {
    __syncthreads();
    if (t + 1 < nk) {
      int ko = (t + 1) * 64;
      gll16(Ag0 + ko, (u16*)As[(t + 1) & 1] + lo0);
      gll16(Ag1 + ko, (u16*)As[(t + 1) & 1] + lo1);
      gll16(Bg0 + ko, (u16*)Bs[(t + 1) & 1] + lo0);
      gll16(Bg1 + ko, (u16*)Bs[(t + 1) & 1] + lo1);
    }
    const u16* as = As[t & 1];
    const u16* bs = Bs[t & 1];
    #pragma unroll
    for (int kk = 0; kk < 2; ++kk) {
      short8 av = *(const short8*)(as + offAv[kk]);
      short8 bv[4];
      #pragma unroll
      for (int i = 0; i < 4; ++i) bv[i] = *(const short8*)(bs + offBv[kk][i]);
      #pragma unroll
      for (int ni = 0; ni < 4; ++ni)
        acc[ni] = __builtin_amdgcn_mfma_f32_16x16x32_bf16(av, bv[ni], acc[ni], 0, 0, 0);
    }
  }

  float* zp = Zp + (size_t)ks * M * 64;
  #pragma unroll
  for (int ni = 0; ni < 4; ++ni) {
    int col = ni * 16 + fr;
    #pragma unroll
    for (int j = 0; j < 4; ++j) {
      int row = m0 + wm + fq * 4 + j;
      zp[(size_t)row * 64 + col] = acc[ni][j];
    }
  }
}

// combine split-K partials; fused dec/Bm/Cm epilogue
__global__ __launch_bounds__(256) void abcd_combine(const float* __restrict__ Zp, const float* __restrict__ bias64,
                                                    float* __restrict__ dec, float* __restrict__ Bm,
                                                    float* __restrict__ Cm, int M) {
  int idx = blockIdx.x * 256 + threadIdx.x;  // < M*16
  int row = idx >> 4, n = idx & 15;
  float zA = bias64[n], zDt = bias64[16 + n], zB = bias64[32 + n], zC = bias64[48 + n];
  #pragma unroll
  for (int ks = 0; ks < 4; ++ks) {
    const float* zp = Zp + ((size_t)ks * M + row) * 64;
    zA += zp[n]; zDt += zp[16 + n]; zB += zp[32 + n]; zC += zp[48 + n];
  }
  size_t o = (size_t)row * NST + n;
  dec[o] = expf(-expf(zA + zDt));
  Bm[o] = zB;
  Cm[o] = zC;
}

// ---------------- depthwise causal conv (k=4) + bias + silu; short8-vectorized ----------------
__global__ __launch_bounds__(256) void conv_silu(const u16* __restrict__ xpg, const float* __restrict__ cw,
                                                 const float* __restrict__ cb, u16* __restrict__ xab) {
  int idx = blockIdx.x * 256 + threadIdx.x;   // < NTOK*DI/8
  int d8 = idx % (DI / 8);
  int token = idx / (DI / 8);
  int t = token % SEQ;
  int d0 = d8 * 8;
  const short8* xv = (const short8*)(xpg + (size_t)token * NIG + d0);
  short8 z8 = {0, 0, 0, 0, 0, 0, 0, 0};
  short8 x3 = (t >= 3) ? xv[-3 * (NIG / 8)] : z8;
  short8 x2 = (t >= 2) ? xv[-2 * (NIG / 8)] : z8;
  short8 x1 = (t >= 1) ? xv[-1 * (NIG / 8)] : z8;
  short8 x0 = xv[0];
  const float4* cw4 = (const float4*)cw;
  float4 cbl = ((const float4*)cb)[d8 * 2], cbh = ((const float4*)cb)[d8 * 2 + 1];
  float cbv[8] = {cbl.x, cbl.y, cbl.z, cbl.w, cbh.x, cbh.y, cbh.z, cbh.w};
  short8 o;
  #pragma unroll
  for (int j = 0; j < 8; ++j) {
    float4 w = cw4[d0 + j];
    float a = cbv[j];
    a = fmaf(b2f((u16)x3[j]), w.x, a);
    a = fmaf(b2f((u16)x2[j]), w.y, a);
    a = fmaf(b2f((u16)x1[j]), w.z, a);
    a = fmaf(b2f((u16)x0[j]), w.w, a);
    o[j] = (short)f2b(siluf_(a));
  }
  *(short8*)(xab + (size_t)token * DI + d0) = o;
}

// ---------------- chunked selective scan ----------------
// phase1: per-chunk local scan from h=0 -> lend[c][b][d][16]; P[c][b][16]=prod(dec)
__global__ __launch_bounds__(256) void scan_phase1(const u16* __restrict__ ub, const float* __restrict__ dec,
                                                   const float* __restrict__ Bm, float* __restrict__ lend,
                                                   float* __restrict__ P) {
  __shared__ float dl[LCH * NST], bl[LCH * NST];
  int bid = blockIdx.x;
  int dblk = bid % 6, b = (bid / 6) % BATCH, c = bid / (6 * BATCH);
  int d = dblk * 256 + threadIdx.x;
  int t0 = c * LCH;
  size_t base16 = (size_t)(b * SEQ + t0) * NST;
  for (int i = threadIdx.x; i < LCH * NST; i += 256) { dl[i] = dec[base16 + i]; bl[i] = Bm[base16 + i]; }
  __syncthreads();
  float h[NST];
  #pragma unroll
  for (int n = 0; n < NST; ++n) h[n] = 0.f;
  const u16* up = ub + (size_t)(b * SEQ + t0) * DI + d;
  for (int t = 0; t < LCH; ++t) {
    float uu = b2f(up[(size_t)t * DI]);
    #pragma unroll
    for (int n = 0; n < NST; ++n) h[n] = fmaf(h[n], dl[t * NST + n], bl[t * NST + n] * uu);
  }
  float* lo = lend + ((size_t)(c * BATCH + b) * DI + d) * NST;
  ((float4*)lo)[0] = make_float4(h[0], h[1], h[2], h[3]);
  ((float4*)lo)[1] = make_float4(h[4], h[5], h[6], h[7]);
  ((float4*)lo)[2] = make_float4(h[8], h[9], h[10], h[11]);
  ((float4*)lo)[3] = make_float4(h[12], h[13], h[14], h[15]);
  if (dblk == 0 && threadIdx.x < NST) {
    float pr = 1.f;
    for (int t = 0; t < LCH; ++t) pr *= dl[t * NST + threadIdx.x];
    P[(size_t)(c * BATCH + b) * NST + threadIdx.x] = pr;
  }
}

// phase2: cross-chunk scan, parallel over (b,d,n); Hin[c] = state entering chunk c
__global__ __launch_bounds__(256) void scan_phase2(const float* __restrict__ lend, const float* __restrict__ P,
                                                   float* __restrict__ Hin) {
  int flat = blockIdx.x * 256 + threadIdx.x;  // < BATCH*DI*NST
  int n = flat & 15;
  int d = (flat >> 4) % DI;
  int b = flat / (DI * NST);
  float h = 0.f;
  for (int c = 0; c < NCH; ++c) {
    size_t idx = ((size_t)(c * BATCH + b) * DI + d) * NST + n;
    Hin[idx] = h;
    h = fmaf(P[(size_t)(c * BATCH + b) * NST + n], h, lend[idx]);
  }
}

// phase3: replay chunk from Hin, emit gy = bf16(silu(gate) * y); gate is cols DI..2DI of xpg
__global__ __launch_bounds__(256) void scan_phase3(const u16* __restrict__ ub, const float* __restrict__ dec,
                                                   const float* __restrict__ Bm, const float* __restrict__ Cm,
                                                   const float* __restrict__ Hin, const u16* __restrict__ xpg,
                                                   u16* __restrict__ gy) {
  __shared__ float dl[LCH * NST], bl[LCH * NST], cl[LCH * NST];
  int bid = blockIdx.x;
  int dblk = bid % 6, b = (bid / 6) % BATCH, c = bid / (6 * BATCH);
  int d = dblk * 256 + threadIdx.x;
  int t0 = c * LCH;
  size_t base16 = (size_t)(b * SEQ + t0) * NST;
  for (int i = threadIdx.x; i < LCH * NST; i += 256) {
    dl[i] = dec[base16 + i]; bl[i] = Bm[base16 + i]; cl[i] = Cm[base16 + i];
  }
  __syncthreads();
  float h[NST];
  const float4* hi = (const float4*)(Hin + ((size_t)(c * BATCH + b) * DI + d) * NST);
  float4 h0 = hi[0], h1 = hi[1], h2 = hi[2], h3 = hi[3];
  h[0]=h0.x; h[1]=h0.y; h[2]=h0.z; h[3]=h0.w; h[4]=h1.x; h[5]=h1.y; h[6]=h1.z; h[7]=h1.w;
  h[8]=h2.x; h[9]=h2.y; h[10]=h2.z; h[11]=h2.w; h[12]=h3.x; h[13]=h3.y; h[14]=h3.z; h[15]=h3.w;
  const u16* up = ub + (size_t)(b * SEQ + t0) * DI + d;
  const u16* gp = xpg + (size_t)(b * SEQ + t0) * NIG + DI + d;
  u16* yp = gy + (size_t)(b * SEQ + t0) * DI + d;
  for (int t = 0; t < LCH; ++t) {
    float uu = b2f(up[(size_t)t * DI]);
    float acc = 0.f;
    #pragma unroll
    for (int n = 0; n < NST; ++n) {
      h[n] = fmaf(h[n], dl[t * NST + n], bl[t * NST + n] * uu);
      acc = fmaf(h[n], cl[t * NST + n], acc);
    }
    float g = b2f(gp[(size_t)t * NIG]);
    yp[(size_t)t * DI] = f2b(siluf_(g) * acc);
  }
}

extern "C" void kernel_launch(void* const* d_in, const int* in_sizes, int n_in,
                              void* d_out, int out_size, void* d_ws, size_t ws_size,
                              hipStream_t stream) {
  const float* x      = (const float*)d_in[0];
  const float* ln_g   = (const float*)d_in[1];
  const float* ln_b   = (const float*)d_in[2];
  const float* W_in   = (const float*)d_in[3];
  const float* b_in   = (const float*)d_in[4];
  const float* conv_w = (const float*)d_in[5];
  const float* conv_b = (const float*)d_in[6];
  const float* W_A    = (const float*)d_in[7];
  const float* b_A    = (const float*)d_in[8];
  const float* W_B    = (const float*)d_in[9];
  const float* b_B    = (const float*)d_in[10];
  const float* W_C    = (const float*)d_in[11];
  const float* b_C    = (const float*)d_in[12];
  const float* W_dt   = (const float*)d_in[13];
  const float* b_dt   = (const float*)d_in[14];
  const float* W_S    = (const float*)d_in[15];
  const float* b_S    = (const float*)d_in[16];
  const float* W_gate = (const float*)d_in[17];
  const float* b_gate = (const float*)d_in[18];
  const float* W_out  = (const float*)d_in[19];
  const float* b_out  = (const float*)d_in[20];
  float* out = (float*)d_out;

  char* p = (char*)d_ws;
  auto alloc = [&](size_t bytes) { char* r = p; p += (bytes + 255) & ~(size_t)255; return r; };
  u16*   Wigb    = (u16*)alloc((size_t)NIG * DM * 2);   // [3072][768] = W_in | W_gate
  float* biasig  = (float*)alloc((size_t)NIG * 4);
  u16*   WSb     = (u16*)alloc((size_t)DI * DI * 2);    // first half of W_S only
  u16*   Woutb   = (u16*)alloc((size_t)DM * DI * 2);
  u16*   Wabcd   = (u16*)alloc((size_t)64 * DI * 2);
  float* bias64  = (float*)alloc(64 * 4);
  u16*   xnb     = (u16*)alloc((size_t)NTOK * DM * 2);
  u16*   xpg     = (u16*)alloc((size_t)NTOK * NIG * 2); // [tok][3072]: xp | gate (bf16)
  u16*   xab     = (u16*)alloc((size_t)NTOK * DI * 2);  // silu(conv) bf16; reused as gy
  u16*   ub      = (u16*)alloc((size_t)NTOK * DI * 2);  // u bf16
  float* Zp      = (float*)alloc((size_t)4 * NTOK * 64 * 4);  // split-K partials
  float* decb    = (float*)alloc((size_t)NTOK * NST * 4);
  float* Bmb     = (float*)alloc((size_t)NTOK * NST * 4);
  float* Cmb     = (float*)alloc((size_t)NTOK * NST * 4);
  float* lend    = (float*)alloc((size_t)NCH * BATCH * DI * NST * 4);
  float* Hin     = (float*)alloc((size_t)NCH * BATCH * DI * NST * 4);
  float* P       = (float*)alloc((size_t)NCH * BATCH * NST * 4);
  u16* gy = xab;

  // weight prep
  cast_ingate<<<(NIG * DM + 255) / 256, 256, 0, stream>>>(W_in, W_gate, b_in, b_gate, Wigb, biasig);
  cast_two<<<(DI * DI / 4 + DM * DI / 4 + 255) / 256, 256, 0, stream>>>(W_S, WSb, DI * DI / 4,
                                                                        W_out, Woutb, DM * DI / 4);
  cast_wabcd<<<(64 * DI + 255) / 256, 256, 0, stream>>>(W_A, W_dt, W_B, W_C, b_A, b_dt, b_B, b_C, Wabcd, bias64);

  ln_kernel<<<NTOK, 256, 0, stream>>>(x, ln_g, ln_b, xnb);

  // fused in|gate GEMM -> xpg bf16
  gemm_bt<2><<<dim3(NIG / 128, NTOK / 128), 256, 0, stream>>>(xnb, Wigb, biasig, nullptr, nullptr,
                                                              nullptr, xpg, NTOK, NIG, DM);

  conv_silu<<<NTOK * (DI / 8) / 256, 256, 0, stream>>>(xpg, conv_w, conv_b, xab);

  // S GEMM with fused u = xa * sigmoid(Sp) -> ub bf16 (aux = xab, same buffer as A operand)
  gemm_bt<1><<<dim3(DI / 128, NTOK / 128), 256, 0, stream>>>(xab, WSb, b_S, nullptr, xab,
                                                             nullptr, ub, NTOK, DI, DI);

  gemm_abcd<<<dim3(NTOK / 64, 4), 256, 0, stream>>>(ub, Wabcd, Zp, NTOK, DI);
  abcd_combine<<<NTOK * 16 / 256, 256, 0, stream>>>(Zp, bias64, decb, Bmb, Cmb, NTOK);

  scan_phase1<<<NCH * BATCH * (DI / 256), 256, 0, stream>>>(ub, decb, Bmb, lend, P);
  scan_phase2<<<BATCH * DI * NST / 256, 256, 0, stream>>>(lend, P, Hin);
  scan_phase3<<<NCH * BATCH * (DI / 256), 256, 0, stream>>>(ub, decb, Bmb, Cmb, Hin, xpg, gy);

  // out GEMM + residual (f32 out)
  gemm_bt<0><<<dim3(DM / 128, NTOK / 128), 256, 0, stream>>>(gy, Woutb, b_out, x, nullptr,
                                                             out, nullptr, NTOK, DM, DI);
}

// Round 11
// 211.722 us; speedup vs baseline: 1.0228x; 1.0228x over previous
//
#include <hip/hip_runtime.h>

// BayesianMambaBlock on MI355X (gfx950).
// LN -> fused (in|gate) GEMM [256² 4-phase pipelined] -> conv+silu -> S GEMM [128² depth-3] (fused u) ->
// abcd GEMM split-K4 + combine -> chunked scan (phase3 fused gate) -> out GEMM [128²] (+resid, f32).

typedef unsigned short u16;
using short8 = __attribute__((ext_vector_type(8))) short;
using f32x4  = __attribute__((ext_vector_type(4))) float;

#define BATCH 2
#define SEQ   2048
#define DM    768
#define DI    1536
#define NIG   (2*DI)        // fused in+gate width 3072
#define NST   16
#define LCH   64
#define NCH   32
#define NTOK  (BATCH*SEQ)   // 4096

__device__ __forceinline__ u16 f2b(float x) {
  unsigned u = __float_as_uint(x);
  u += 0x7FFFu + ((u >> 16) & 1u);   // round-to-nearest-even bf16
  return (u16)(u >> 16);
}
__device__ __forceinline__ float b2f(u16 v) { return __uint_as_float((unsigned)v << 16); }
__device__ __forceinline__ float sigmoidf_(float x) { return 1.f / (1.f + expf(-x)); }
__device__ __forceinline__ float siluf_(float x) { return x / (1.f + expf(-x)); }

// ---------------- f32 -> bf16 casts: two buffers in one launch ----------------
__global__ __launch_bounds__(256) void cast_two(const float* __restrict__ in1, u16* __restrict__ out1, int n1,
                                                const float* __restrict__ in2, u16* __restrict__ out2, int n2) {
  int i = blockIdx.x * 256 + threadIdx.x;
  if (i < n1) {
    float4 v = ((const float4*)in1)[i];
    ushort4 o; o.x = f2b(v.x); o.y = f2b(v.y); o.z = f2b(v.z); o.w = f2b(v.w);
    ((ushort4*)out1)[i] = o;
  } else if (i - n1 < n2) {
    int j = i - n1;
    float4 v = ((const float4*)in2)[j];
    ushort4 o; o.x = f2b(v.x); o.y = f2b(v.y); o.z = f2b(v.z); o.w = f2b(v.w);
    ((ushort4*)out2)[j] = o;
  }
}

// ---------------- concat W_in|W_gate -> bf16 [3072][768] + bias3072 ----------------
__global__ __launch_bounds__(256) void cast_ingate(const float* __restrict__ Wi, const float* __restrict__ Wg,
                                                   const float* __restrict__ bi, const float* __restrict__ bg,
                                                   u16* __restrict__ Wb, float* __restrict__ bias) {
  int i = blockIdx.x * 256 + threadIdx.x;   // < NIG*DM
  if (i >= NIG * DM) return;
  int r = i / DM, c = i % DM;
  Wb[i] = f2b(r < DI ? Wi[(size_t)r * DM + c] : Wg[(size_t)(r - DI) * DM + c]);
  if (i < NIG) bias[i] = (i < DI) ? bi[i] : bg[i - DI];
}

// ---------------- concat W_A/W_dt/W_B/W_C -> bf16 [64][DI] + bias64 ----------------
__global__ __launch_bounds__(256) void cast_wabcd(const float* __restrict__ WA, const float* __restrict__ Wdt,
                                                  const float* __restrict__ WB, const float* __restrict__ WC,
                                                  const float* __restrict__ bA, const float* __restrict__ bdt,
                                                  const float* __restrict__ bB, const float* __restrict__ bC,
                                                  u16* __restrict__ Wb, float* __restrict__ bias64) {
  int i = blockIdx.x * 256 + threadIdx.x;   // < 64*DI
  if (i >= 64 * DI) return;
  int r = i / DI, c = i % DI;
  const float* src = (r < 16) ? WA + (size_t)r * DI
                  : (r < 32) ? Wdt + (size_t)(r - 16) * DI
                  : (r < 48) ? WB + (size_t)(r - 32) * DI
                             : WC + (size_t)(r - 48) * DI;
  Wb[i] = f2b(src[c]);
  if (i < 64) bias64[i] = (i < 16) ? bA[i] : (i < 32) ? bdt[i - 16] : (i < 48) ? bB[i - 32] : bC[i - 48];
}

// ---------------- LayerNorm -> bf16 ----------------
__global__ __launch_bounds__(256) void ln_kernel(const float* __restrict__ x, const float* __restrict__ g,
                                                 const float* __restrict__ bb, u16* __restrict__ xn) {
  int m = blockIdx.x, tid = threadIdx.x;
  const float* xr = x + (size_t)m * DM;
  float v0 = xr[tid], v1 = xr[tid + 256], v2 = xr[tid + 512];
  float s  = v0 + v1 + v2;
  float s2 = fmaf(v0, v0, fmaf(v1, v1, v2 * v2));
  #pragma unroll
  for (int off = 32; off > 0; off >>= 1) { s += __shfl_down(s, off); s2 += __shfl_down(s2, off); }
  __shared__ float sh[8];
  int wave = tid >> 6, lane = tid & 63;
  if (lane == 0) { sh[wave] = s; sh[4 + wave] = s2; }
  __syncthreads();
  float S1 = sh[0] + sh[1] + sh[2] + sh[3];
  float S2 = sh[4] + sh[5] + sh[6] + sh[7];
  float mu = S1 * (1.f / DM);
  float var = S2 * (1.f / DM) - mu * mu;
  float rs = rsqrtf(var + 1e-5f);
  u16* o = xn + (size_t)m * DM;
  o[tid]       = f2b((v0 - mu) * rs * g[tid]       + bb[tid]);
  o[tid + 256] = f2b((v1 - mu) * rs * g[tid + 256] + bb[tid + 256]);
  o[tid + 512] = f2b((v2 - mu) * rs * g[tid + 512] + bb[tid + 512]);
}

__device__ __forceinline__ void gll16(const void* g, void* l) {
  __builtin_amdgcn_global_load_lds((const __attribute__((address_space(1))) void*)g,
                                   (__attribute__((address_space(3))) void*)l, 16, 0, 0);
}

// ---------------- 256x256 4-phase pipelined GEMM (in|gate): Cb = bf16(A*B^T + bias) ----------------
// 512 thr / 8 waves (2Mx4N), wave tile 128x64, BK=64, 2 LDS buffers (128KB, 1 block/CU).
// Per K-tile: top {vmcnt(0); s_barrier}; 4 phases {stage-ahead unit; ds_read 8 frags; setprio(1); 16 MFMA; setprio(0); s_barrier}.
// Staging units of tile t+1 are issued 2-4 phases before tile t+1's top wait.
__global__ __launch_bounds__(512) void gemm256(const u16* __restrict__ A, const u16* __restrict__ B,
                                               const float* __restrict__ bias, u16* __restrict__ Cb,
                                               int M, int N, int K) {
  __shared__ __align__(16) u16 As[2][256 * 64];
  __shared__ __align__(16) u16 Bs[2][256 * 64];
  const int tid = threadIdx.x, wave = tid >> 6, lane = tid & 63;

  const int nbx = gridDim.x, nwg = nbx * gridDim.y;
  const int orig = blockIdx.y * nbx + blockIdx.x;
  const int cpx = nwg >> 3;
  const int swz = (orig & 7) * cpx + (orig >> 3);
  const int m0 = (swz / nbx) * 256, n0 = (swz % nbx) * 256;

  const int wm = (wave >> 2) * 128, wn = (wave & 3) * 64;
  const int fr = lane & 15, fq = lane >> 4;
  f32x4 acc[8][4] = {};

  // staging: tile = 256 rows x 64 k; 4 units of 64 rows; chunk (16B) per thread per unit.
  // chunk c (= unit*512 + tid): row = c>>3, LDS slot c&7 holds global k-chunk (c&7)^(row&7).
  const int strow = tid >> 3;                       // 0..63 (row within unit)
  const int gk8 = ((tid & 7) ^ (strow & 7)) * 8;    // swizzled k-chunk element offset
  const u16* Ags = A + (size_t)(m0 + strow) * K + gk8;
  const u16* Bgs = B + (size_t)(n0 + strow) * K + gk8;
  const int ldst = wave * 512;                      // u16; HW adds lane*16B

  // ds_read offsets (u16 units): row r, k-chunk q stored at slot q^(r&7); r&7 == fr&7 here.
  int offA[2][8], offB[2][4];
  #pragma unroll
  for (int ks = 0; ks < 2; ++ks) {
    #pragma unroll
    for (int i = 0; i < 8; ++i)
      offA[ks][i] = (wm + i * 16 + fr) * 64 + (((ks * 4 + fq) ^ (fr & 7))) * 8;
    #pragma unroll
    for (int j = 0; j < 4; ++j)
      offB[ks][j] = (wn + j * 16 + fr) * 64 + (((ks * 4 + fq) ^ (fr & 7))) * 8;
  }

#define STG256(kt, s, bb) { \
    gll16(Ags + (size_t)(s) * 64 * K + (size_t)(kt) * 64, (u16*)As[bb] + (s) * 4096 + ldst); \
    gll16(Bgs + (size_t)(s) * 64 * K + (size_t)(kt) * 64, (u16*)Bs[bb] + (s) * 4096 + ldst); }
#define PH256(as_, bs_, ks, mh) { \
    short8 av[4], bv[4]; \
    _Pragma("unroll") for (int i = 0; i < 4; ++i) av[i] = *(const short8*)((as_) + offA[ks][(mh) * 4 + i]); \
    _Pragma("unroll") for (int j = 0; j < 4; ++j) bv[j] = *(const short8*)((bs_) + offB[ks][j]); \
    __builtin_amdgcn_s_setprio(1); \
    _Pragma("unroll") for (int i = 0; i < 4; ++i) \
      _Pragma("unroll") for (int j = 0; j < 4; ++j) \
        acc[(mh) * 4 + i][j] = __builtin_amdgcn_mfma_f32_16x16x32_bf16(av[i], bv[j], acc[(mh) * 4 + i][j], 0, 0, 0); \
    __builtin_amdgcn_s_setprio(0); }

  const int nt = K >> 6;
  STG256(0, 0, 0); STG256(0, 1, 0); STG256(0, 2, 0); STG256(0, 3, 0);

  for (int t = 0; t < nt; ++t) {
    const int cur = t & 1, nxt = cur ^ 1;
    const bool pf = (t + 1 < nt);
    asm volatile("s_waitcnt vmcnt(0)" ::: "memory");   // tile t landed (issued phases ago)
    __builtin_amdgcn_s_barrier();                      // all waves' loads visible; prior reads of nxt done
    const u16* as = As[cur]; const u16* bs = Bs[cur];
    if (pf) { STG256(t + 1, 0, nxt); STG256(t + 1, 1, nxt); }
    PH256(as, bs, 0, 0);
    __builtin_amdgcn_s_barrier();
    if (pf) STG256(t + 1, 2, nxt);
    PH256(as, bs, 0, 1);
    __builtin_amdgcn_s_barrier();
    if (pf) STG256(t + 1, 3, nxt);
    PH256(as, bs, 1, 0);
    __builtin_amdgcn_s_barrier();
    PH256(as, bs, 1, 1);
  }
#undef STG256
#undef PH256

  #pragma unroll
  for (int ni = 0; ni < 4; ++ni) {
    int col = n0 + wn + ni * 16 + fr;
    float bv_ = bias[col];
    #pragma unroll
    for (int mi = 0; mi < 8; ++mi) {
      int row = m0 + wm + mi * 16 + fq * 4;
      #pragma unroll
      for (int j = 0; j < 4; ++j) {
        size_t off = (size_t)(row + j) * N + col;
        Cb[off] = f2b(acc[mi][ni][j] + bv_);
      }
    }
  }
}

// ---------------- bf16 MFMA NT-GEMM (128²): acc = A[M][K] * B[N][K]^T + bias ----------------
// 512 threads, 8 waves, 128x128 block tile, 32x64 wave tile, BK=32.
// Depth-3 pipeline: 4 LDS buffers, counted vmcnt(4) + raw s_barrier; tail drains 4->2->0.
// MODE 0: C f32 = acc + bias + aux(resid, f32);  MODE 1: Cb = bf16(b2f(auxb)*sigmoid(acc+bias))
template <int MODE>
__global__ __launch_bounds__(512) void gemm_bt(const u16* __restrict__ A, const u16* __restrict__ B,
                                               const float* __restrict__ bias, const float* __restrict__ aux,
                                               const u16* __restrict__ auxb,
                                               float* __restrict__ C, u16* __restrict__ Cb,
                                               int M, int N, int K) {
  __shared__ __align__(16) u16 As[4][128 * 32];
  __shared__ __align__(16) u16 Bs[4][128 * 32];
  const int tid = threadIdx.x, wave = tid >> 6, lane = tid & 63;

  const int nbx = gridDim.x, nwg = nbx * gridDim.y;
  const int orig = blockIdx.y * nbx + blockIdx.x;
  const int cpx = nwg >> 3;
  const int swz = (orig & 7) * cpx + (orig >> 3);
  const int m0 = (swz / nbx) * 128, n0 = (swz % nbx) * 128;

  const int wm = (wave >> 1) * 32, wn = (wave & 1) * 64;
  const int fr = lane & 15, fq = lane >> 4;
  f32x4 acc[2][4] = {};

  const int c0 = tid;   // 512 chunks of 16B cover 128x32
  const u16* Ag0 = A + (size_t)(m0 + (c0 >> 2)) * K + ((c0 & 3) ^ ((c0 >> 3) & 3)) * 8;
  const u16* Bg0 = B + (size_t)(n0 + (c0 >> 2)) * K + ((c0 & 3) ^ ((c0 >> 3) & 3)) * 8;
  const int lofs = (wave * 64) * 8;

  int offA[2], offB[4];
  #pragma unroll
  for (int i = 0; i < 2; ++i) {
    int ra = wm + i * 16 + fr;
    offA[i] = ra * 32 + (fq ^ ((ra >> 1) & 3)) * 8;
  }
  #pragma unroll
  for (int i = 0; i < 4; ++i) {
    int rb = wn + i * 16 + fr;
    offB[i] = rb * 32 + (fq ^ ((rb >> 1) & 3)) * 8;
  }

  const int nk = K >> 5;

#define STAGE_BT(tt) { gll16(Ag0 + (tt) * 32, (u16*)As[(tt) & 3] + lofs); \
                       gll16(Bg0 + (tt) * 32, (u16*)Bs[(tt) & 3] + lofs); }
#define COMPUTE_BT(tt) { const u16* as_ = As[(tt) & 3]; const u16* bs_ = Bs[(tt) & 3]; \
    short8 av[2], bv[4]; \
    _Pragma("unroll") for (int i = 0; i < 2; ++i) av[i] = *(const short8*)(as_ + offA[i]); \
    _Pragma("unroll") for (int i = 0; i < 4; ++i) bv[i] = *(const short8*)(bs_ + offB[i]); \
    __builtin_amdgcn_s_setprio(1); \
    _Pragma("unroll") for (int mi = 0; mi < 2; ++mi) \
      _Pragma("unroll") for (int ni = 0; ni < 4; ++ni) \
        acc[mi][ni] = __builtin_amdgcn_mfma_f32_16x16x32_bf16(av[mi], bv[ni], acc[mi][ni], 0, 0, 0); \
    __builtin_amdgcn_s_setprio(0); }

  STAGE_BT(0); STAGE_BT(1); STAGE_BT(2);   // 6 loads in flight per wave

  for (int t = 0; t < nk - 3; ++t) {
    asm volatile("s_waitcnt vmcnt(4)" ::: "memory");   // tile t arrived; t+1,t+2 in flight
    __builtin_amdgcn_s_barrier();
    STAGE_BT(t + 3);
    COMPUTE_BT(t);
  }
  asm volatile("s_waitcnt vmcnt(4)" ::: "memory");
  __builtin_amdgcn_s_barrier();
  COMPUTE_BT(nk - 3);
  asm volatile("s_waitcnt vmcnt(2)" ::: "memory");
  __builtin_amdgcn_s_barrier();
  COMPUTE_BT(nk - 2);
  asm volatile("s_waitcnt vmcnt(0)" ::: "memory");
  __builtin_amdgcn_s_barrier();
  COMPUTE_BT(nk - 1);
#undef STAGE_BT
#undef COMPUTE_BT

  #pragma unroll
  for (int ni = 0; ni < 4; ++ni) {
    int col = n0 + wn + ni * 16 + fr;
    float bv_ = bias[col];
    #pragma unroll
    for (int mi = 0; mi < 2; ++mi) {
      int row = m0 + wm + mi * 16 + fq * 4;
      #pragma unroll
      for (int j = 0; j < 4; ++j) {
        size_t off = (size_t)(row + j) * N + col;
        float z = acc[mi][ni][j] + bv_;
        if (MODE == 0) {
          C[off] = z + aux[off];
        } else {
          Cb[off] = f2b(b2f(auxb[off]) * sigmoidf_(z));
        }
      }
    }
  }
}

// ---------------- abcd GEMM split-K: Zp[ks] = ub[M][Kq] * Wabcd[64][Kq]^T ----------------
__global__ __launch_bounds__(256) void gemm_abcd(const u16* __restrict__ A, const u16* __restrict__ B,
                                                 float* __restrict__ Zp, int M, int K) {
  __shared__ __align__(16) u16 As[2][64 * 64];
  __shared__ __align__(16) u16 Bs[2][64 * 64];
  const int tid = threadIdx.x, wave = tid >> 6, lane = tid & 63;
  const int m0 = blockIdx.x * 64;
  const int ks = blockIdx.y;
  const int Kq = K >> 2;            // 384
  const int kbase = ks * Kq;
  const int wm = wave * 16;
  const int fr = lane & 15, fq = lane >> 4;
  f32x4 acc[4] = {};

  const int c0 = tid, c1 = tid + 256;
  const u16* Ag0 = A + (size_t)(m0 + (c0 >> 3)) * K + kbase + ((c0 & 7) ^ ((c0 >> 3) & 7)) * 8;
  const u16* Ag1 = A + (size_t)(m0 + (c1 >> 3)) * K + kbase + ((c1 & 7) ^ ((c1 >> 3) & 7)) * 8;
  const u16* Bg0 = B + (size_t)(c0 >> 3) * K + kbase + ((c0 & 7) ^ ((c0 >> 3) & 7)) * 8;
  const u16* Bg1 = B + (size_t)(c1 >> 3) * K + kbase + ((c1 & 7) ^ ((c1 >> 3) & 7)) * 8;
  const int lo0 = (wave * 64) * 8;
  const int lo1 = (256 + wave * 64) * 8;

  int offAv[2], offBv[2][4];
  {
    int r = wm + fr;
    #pragma unroll
    for (int kk = 0; kk < 2; ++kk) offAv[kk] = r * 64 + ((kk * 4 + fq) ^ (r & 7)) * 8;
    #pragma unroll
    for (int i = 0; i < 4; ++i) {
      int rb = i * 16 + fr;
      #pragma unroll
      for (int kk = 0; kk < 2; ++kk) offBv[kk][i] = rb * 64 + ((kk * 4 + fq) ^ (rb & 7)) * 8;
    }
  }

  const int nk = Kq >> 6;   // 6
  gll16(Ag0, (u16*)As[0] + lo0);
  gll16(Ag1, (u16*)As[0] + lo1);
  gll16(Bg0, (u16*)Bs[0] + lo0);
  gll16(Bg1, (u16*)Bs[0] + lo1);

  for (int t = 0; t < nk; ++t) {
    __syncthreads();
    if (t + 1 < nk) {
      int ko = (t + 1) * 64;
      gll16(Ag0 + ko, (u16*)As[(t + 1) & 1] + lo0);
      gll16(Ag1 + ko, (u16*)As[(t + 1) & 1] + lo1);
      gll16(Bg0 + ko, (u16*)Bs[(t + 1) & 1] + lo0);
      gll16(Bg1 + ko, (u16*)Bs[(t + 1) & 1] + lo1);
    }
    const u16* as = As[t & 1];
    const u16* bs = Bs[t & 1];
    #pragma unroll
    for (int kk = 0; kk < 2; ++kk) {
      short8 av = *(const short8*)(as + offAv[kk]);
      short8 bv[4];
      #pragma unroll
      for (int i = 0; i < 4; ++i) bv[i] = *(const short8*)(bs + offBv[kk][i]);
      #pragma unroll
      for (int ni = 0; ni < 4; ++ni)
        acc[ni] = __builtin_amdgcn_mfma_f32_16x16x32_bf16(av, bv[ni], acc[ni], 0, 0, 0);
    }
  }

  float* zp = Zp + (size_t)ks * M * 64;
  #pragma unroll
  for (int ni = 0; ni < 4; ++ni) {
    int col = ni * 16 + fr;
    #pragma unroll
    for (int j = 0; j < 4; ++j) {
      int row = m0 + wm + fq * 4 + j;
      zp[(size_t)row * 64 + col] = acc[ni][j];
    }
  }
}

// combine split-K partials; fused dec/Bm/Cm epilogue
__global__ __launch_bounds__(256) void abcd_combine(const float* __restrict__ Zp, const float* __restrict__ bias64,
                                                    float* __restrict__ dec, float* __restrict__ Bm,
                                                    float* __restrict__ Cm, int M) {
  int idx = blockIdx.x * 256 + threadIdx.x;  // < M*16
  int row = idx >> 4, n = idx & 15;
  float zA = bias64[n], zDt = bias64[16 + n], zB = bias64[32 + n], zC = bias64[48 + n];
  #pragma unroll
  for (int ks = 0; ks < 4; ++ks) {
    const float* zp = Zp + ((size_t)ks * M + row) * 64;
    zA += zp[n]; zDt += zp[16 + n]; zB += zp[32 + n]; zC += zp[48 + n];
  }
  size_t o = (size_t)row * NST + n;
  dec[o] = expf(-expf(zA + zDt));
  Bm[o] = zB;
  Cm[o] = zC;
}

// ---------------- depthwise causal conv (k=4) + bias + silu; short8-vectorized ----------------
__global__ __launch_bounds__(256) void conv_silu(const u16* __restrict__ xpg, const float* __restrict__ cw,
                                                 const float* __restrict__ cb, u16* __restrict__ xab) {
  int idx = blockIdx.x * 256 + threadIdx.x;   // < NTOK*DI/8
  int d8 = idx % (DI / 8);
  int token = idx / (DI / 8);
  int t = token % SEQ;
  int d0 = d8 * 8;
  const short8* xv = (const short8*)(xpg + (size_t)token * NIG + d0);
  short8 z8 = {0, 0, 0, 0, 0, 0, 0, 0};
  short8 x3 = (t >= 3) ? xv[-3 * (NIG / 8)] : z8;
  short8 x2 = (t >= 2) ? xv[-2 * (NIG / 8)] : z8;
  short8 x1 = (t >= 1) ? xv[-1 * (NIG / 8)] : z8;
  short8 x0 = xv[0];
  const float4* cw4 = (const float4*)cw;
  float4 cbl = ((const float4*)cb)[d8 * 2], cbh = ((const float4*)cb)[d8 * 2 + 1];
  float cbv[8] = {cbl.x, cbl.y, cbl.z, cbl.w, cbh.x, cbh.y, cbh.z, cbh.w};
  short8 o;
  #pragma unroll
  for (int j = 0; j < 8; ++j) {
    float4 w = cw4[d0 + j];
    float a = cbv[j];
    a = fmaf(b2f((u16)x3[j]), w.x, a);
    a = fmaf(b2f((u16)x2[j]), w.y, a);
    a = fmaf(b2f((u16)x1[j]), w.z, a);
    a = fmaf(b2f((u16)x0[j]), w.w, a);
    o[j] = (short)f2b(siluf_(a));
  }
  *(short8*)(xab + (size_t)token * DI + d0) = o;
}

// ---------------- chunked selective scan ----------------
__global__ __launch_bounds__(256) void scan_phase1(const u16* __restrict__ ub, const float* __restrict__ dec,
                                                   const float* __restrict__ Bm, float* __restrict__ lend,
                                                   float* __restrict__ P) {
  __shared__ float dl[LCH * NST], bl[LCH * NST];
  int bid = blockIdx.x;
  int dblk = bid % 6, b = (bid / 6) % BATCH, c = bid / (6 * BATCH);
  int d = dblk * 256 + threadIdx.x;
  int t0 = c * LCH;
  size_t base16 = (size_t)(b * SEQ + t0) * NST;
  for (int i = threadIdx.x; i < LCH * NST; i += 256) { dl[i] = dec[base16 + i]; bl[i] = Bm[base16 + i]; }
  __syncthreads();
  float h[NST];
  #pragma unroll
  for (int n = 0; n < NST; ++n) h[n] = 0.f;
  const u16* up = ub + (size_t)(b * SEQ + t0) * DI + d;
  for (int t = 0; t < LCH; ++t) {
    float uu = b2f(up[(size_t)t * DI]);
    #pragma unroll
    for (int n = 0; n < NST; ++n) h[n] = fmaf(h[n], dl[t * NST + n], bl[t * NST + n] * uu);
  }
  float* lo = lend + ((size_t)(c * BATCH + b) * DI + d) * NST;
  ((float4*)lo)[0] = make_float4(h[0], h[1], h[2], h[3]);
  ((float4*)lo)[1] = make_float4(h[4], h[5], h[6], h[7]);
  ((float4*)lo)[2] = make_float4(h[8], h[9], h[10], h[11]);
  ((float4*)lo)[3] = make_float4(h[12], h[13], h[14], h[15]);
  if (dblk == 0 && threadIdx.x < NST) {
    float pr = 1.f;
    for (int t = 0; t < LCH; ++t) pr *= dl[t * NST + threadIdx.x];
    P[(size_t)(c * BATCH + b) * NST + threadIdx.x] = pr;
  }
}

__global__ __launch_bounds__(256) void scan_phase2(const float* __restrict__ lend, const float* __restrict__ P,
                                                   float* __restrict__ Hin) {
  int flat = blockIdx.x * 256 + threadIdx.x;  // < BATCH*DI*NST
  int n = flat & 15;
  int d = (flat >> 4) % DI;
  int b = flat / (DI * NST);
  float h = 0.f;
  for (int c = 0; c < NCH; ++c) {
    size_t idx = ((size_t)(c * BATCH + b) * DI + d) * NST + n;
    Hin[idx] = h;
    h = fmaf(P[(size_t)(c * BATCH + b) * NST + n], h, lend[idx]);
  }
}

__global__ __launch_bounds__(256) void scan_phase3(const u16* __restrict__ ub, const float* __restrict__ dec,
                                                   const float* __restrict__ Bm, const float* __restrict__ Cm,
                                                   const float* __restrict__ Hin, const u16* __restrict__ xpg,
                                                   u16* __restrict__ gy) {
  __shared__ float dl[LCH * NST], bl[LCH * NST], cl[LCH * NST];
  int bid = blockIdx.x;
  int dblk = bid % 6, b = (bid / 6) % BATCH, c = bid / (6 * BATCH);
  int d = dblk * 256 + threadIdx.x;
  int t0 = c * LCH;
  size_t base16 = (size_t)(b * SEQ + t0) * NST;
  for (int i = threadIdx.x; i < LCH * NST; i += 256) {
    dl[i] = dec[base16 + i]; bl[i] = Bm[base16 + i]; cl[i] = Cm[base16 + i];
  }
  __syncthreads();
  float h[NST];
  const float4* hi = (const float4*)(Hin + ((size_t)(c * BATCH + b) * DI + d) * NST);
  float4 h0 = hi[0], h1 = hi[1], h2 = hi[2], h3 = hi[3];
  h[0]=h0.x; h[1]=h0.y; h[2]=h0.z; h[3]=h0.w; h[4]=h1.x; h[5]=h1.y; h[6]=h1.z; h[7]=h1.w;
  h[8]=h2.x; h[9]=h2.y; h[10]=h2.z; h[11]=h2.w; h[12]=h3.x; h[13]=h3.y; h[14]=h3.z; h[15]=h3.w;
  const u16* up = ub + (size_t)(b * SEQ + t0) * DI + d;
  const u16* gp = xpg + (size_t)(b * SEQ + t0) * NIG + DI + d;
  u16* yp = gy + (size_t)(b * SEQ + t0) * DI + d;
  for (int t = 0; t < LCH; ++t) {
    float uu = b2f(up[(size_t)t * DI]);
    float acc = 0.f;
    #pragma unroll
    for (int n = 0; n < NST; ++n) {
      h[n] = fmaf(h[n], dl[t * NST + n], bl[t * NST + n] * uu);
      acc = fmaf(h[n], cl[t * NST + n], acc);
    }
    float g = b2f(gp[(size_t)t * NIG]);
    yp[(size_t)t * DI] = f2b(siluf_(g) * acc);
  }
}

extern "C" void kernel_launch(void* const* d_in, const int* in_sizes, int n_in,
                              void* d_out, int out_size, void* d_ws, size_t ws_size,
                              hipStream_t stream) {
  const float* x      = (const float*)d_in[0];
  const float* ln_g   = (const float*)d_in[1];
  const float* ln_b   = (const float*)d_in[2];
  const float* W_in   = (const float*)d_in[3];
  const float* b_in   = (const float*)d_in[4];
  const float* conv_w = (const float*)d_in[5];
  const float* conv_b = (const float*)d_in[6];
  const float* W_A    = (const float*)d_in[7];
  const float* b_A    = (const float*)d_in[8];
  const float* W_B    = (const float*)d_in[9];
  const float* b_B    = (const float*)d_in[10];
  const float* W_C    = (const float*)d_in[11];
  const float* b_C    = (const float*)d_in[12];
  const float* W_dt   = (const float*)d_in[13];
  const float* b_dt   = (const float*)d_in[14];
  const float* W_S    = (const float*)d_in[15];
  const float* b_S    = (const float*)d_in[16];
  const float* W_gate = (const float*)d_in[17];
  const float* b_gate = (const float*)d_in[18];
  const float* W_out  = (const float*)d_in[19];
  const float* b_out  = (const float*)d_in[20];
  float* out = (float*)d_out;

  char* p = (char*)d_ws;
  auto alloc = [&](size_t bytes) { char* r = p; p += (bytes + 255) & ~(size_t)255; return r; };
  u16*   Wigb    = (u16*)alloc((size_t)NIG * DM * 2);   // [3072][768] = W_in | W_gate
  float* biasig  = (float*)alloc((size_t)NIG * 4);
  u16*   WSb     = (u16*)alloc((size_t)DI * DI * 2);    // first half of W_S only
  u16*   Woutb   = (u16*)alloc((size_t)DM * DI * 2);
  u16*   Wabcd   = (u16*)alloc((size_t)64 * DI * 2);
  float* bias64  = (float*)alloc(64 * 4);
  u16*   xnb     = (u16*)alloc((size_t)NTOK * DM * 2);
  u16*   xpg     = (u16*)alloc((size_t)NTOK * NIG * 2); // [tok][3072]: xp | gate (bf16)
  u16*   xab     = (u16*)alloc((size_t)NTOK * DI * 2);  // silu(conv) bf16; reused as gy
  u16*   ub      = (u16*)alloc((size_t)NTOK * DI * 2);  // u bf16
  float* Zp      = (float*)alloc((size_t)4 * NTOK * 64 * 4);  // split-K partials
  float* decb    = (float*)alloc((size_t)NTOK * NST * 4);
  float* Bmb     = (float*)alloc((size_t)NTOK * NST * 4);
  float* Cmb     = (float*)alloc((size_t)NTOK * NST * 4);
  float* lend    = (float*)alloc((size_t)NCH * BATCH * DI * NST * 4);
  float* Hin     = (float*)alloc((size_t)NCH * BATCH * DI * NST * 4);
  float* P       = (float*)alloc((size_t)NCH * BATCH * NST * 4);
  u16* gy = xab;

  // weight prep
  cast_ingate<<<(NIG * DM + 255) / 256, 256, 0, stream>>>(W_in, W_gate, b_in, b_gate, Wigb, biasig);
  cast_two<<<(DI * DI / 4 + DM * DI / 4 + 255) / 256, 256, 0, stream>>>(W_S, WSb, DI * DI / 4,
                                                                        W_out, Woutb, DM * DI / 4);
  cast_wabcd<<<(64 * DI + 255) / 256, 256, 0, stream>>>(W_A, W_dt, W_B, W_C, b_A, b_dt, b_B, b_C, Wabcd, bias64);

  ln_kernel<<<NTOK, 256, 0, stream>>>(x, ln_g, ln_b, xnb);

  // fused in|gate GEMM -> xpg bf16 (256² 4-phase)
  gemm256<<<dim3(NIG / 256, NTOK / 256), 512, 0, stream>>>(xnb, Wigb, biasig, xpg, NTOK, NIG, DM);

  conv_silu<<<NTOK * (DI / 8) / 256, 256, 0, stream>>>(xpg, conv_w, conv_b, xab);

  // S GEMM with fused u = xa * sigmoid(Sp) -> ub bf16 (aux = xab, same buffer as A operand)
  gemm_bt<1><<<dim3(DI / 128, NTOK / 128), 512, 0, stream>>>(xab, WSb, b_S, nullptr, xab,
                                                             nullptr, ub, NTOK, DI, DI);

  gemm_abcd<<<dim3(NTOK / 64, 4), 256, 0, stream>>>(ub, Wabcd, Zp, NTOK, DI);
  abcd_combine<<<NTOK * 16 / 256, 256, 0, stream>>>(Zp, bias64, decb, Bmb, Cmb, NTOK);

  scan_phase1<<<NCH * BATCH * (DI / 256), 256, 0, stream>>>(ub, decb, Bmb, lend, P);
  scan_phase2<<<BATCH * DI * NST / 256, 256, 0, stream>>>(lend, P, Hin);
  scan_phase3<<<NCH * BATCH * (DI / 256), 256, 0, stream>>>(ub, decb, Bmb, Cmb, Hin, xpg, gy);

  // out GEMM + residual (f32 out)
  gemm_bt<0><<<dim3(DM / 128, NTOK / 128), 512, 0, stream>>>(gy, Woutb, b_out, x, nullptr,
                                                             out, nullptr, NTOK, DM, DI);
}

// Round 12
// 206.981 us; speedup vs baseline: 1.0462x; 1.0229x over previous
//
#include <hip/hip_runtime.h>

// BayesianMambaBlock on MI355X (gfx950).
// LN -> fused (in|gate) GEMM -> conv+silu -> S GEMM (fused u) -> abcd GEMM split-K4 + combine ->
// chunked scan (phase3 fused gate) -> out GEMM (+resid, f32).
// gemm_bt: 512 thr / 8 waves, 128x128 tile, 32x64 wave tile, BK=32, depth-4 pipeline
// (5 LDS buffers = 80KB, 2 blocks/CU), counted vmcnt(6) + raw s_barrier, setprio around MFMA,
// chunk-XOR LDS swizzle, XCD-aware block swizzle.

typedef unsigned short u16;
using short8 = __attribute__((ext_vector_type(8))) short;
using f32x4  = __attribute__((ext_vector_type(4))) float;

#define BATCH 2
#define SEQ   2048
#define DM    768
#define DI    1536
#define NIG   (2*DI)        // fused in+gate width 3072
#define NST   16
#define LCH   64
#define NCH   32
#define NTOK  (BATCH*SEQ)   // 4096

__device__ __forceinline__ u16 f2b(float x) {
  unsigned u = __float_as_uint(x);
  u += 0x7FFFu + ((u >> 16) & 1u);   // round-to-nearest-even bf16
  return (u16)(u >> 16);
}
__device__ __forceinline__ float b2f(u16 v) { return __uint_as_float((unsigned)v << 16); }
__device__ __forceinline__ float sigmoidf_(float x) { return 1.f / (1.f + expf(-x)); }
__device__ __forceinline__ float siluf_(float x) { return x / (1.f + expf(-x)); }

// ---------------- f32 -> bf16 casts: two buffers in one launch ----------------
__global__ __launch_bounds__(256) void cast_two(const float* __restrict__ in1, u16* __restrict__ out1, int n1,
                                                const float* __restrict__ in2, u16* __restrict__ out2, int n2) {
  int i = blockIdx.x * 256 + threadIdx.x;
  if (i < n1) {
    float4 v = ((const float4*)in1)[i];
    ushort4 o; o.x = f2b(v.x); o.y = f2b(v.y); o.z = f2b(v.z); o.w = f2b(v.w);
    ((ushort4*)out1)[i] = o;
  } else if (i - n1 < n2) {
    int j = i - n1;
    float4 v = ((const float4*)in2)[j];
    ushort4 o; o.x = f2b(v.x); o.y = f2b(v.y); o.z = f2b(v.z); o.w = f2b(v.w);
    ((ushort4*)out2)[j] = o;
  }
}

// ---------------- concat W_in|W_gate -> bf16 [3072][768] + bias3072 ----------------
__global__ __launch_bounds__(256) void cast_ingate(const float* __restrict__ Wi, const float* __restrict__ Wg,
                                                   const float* __restrict__ bi, const float* __restrict__ bg,
                                                   u16* __restrict__ Wb, float* __restrict__ bias) {
  int i = blockIdx.x * 256 + threadIdx.x;   // < NIG*DM
  if (i >= NIG * DM) return;
  int r = i / DM, c = i % DM;
  Wb[i] = f2b(r < DI ? Wi[(size_t)r * DM + c] : Wg[(size_t)(r - DI) * DM + c]);
  if (i < NIG) bias[i] = (i < DI) ? bi[i] : bg[i - DI];
}

// ---------------- concat W_A/W_dt/W_B/W_C -> bf16 [64][DI] + bias64 ----------------
__global__ __launch_bounds__(256) void cast_wabcd(const float* __restrict__ WA, const float* __restrict__ Wdt,
                                                  const float* __restrict__ WB, const float* __restrict__ WC,
                                                  const float* __restrict__ bA, const float* __restrict__ bdt,
                                                  const float* __restrict__ bB, const float* __restrict__ bC,
                                                  u16* __restrict__ Wb, float* __restrict__ bias64) {
  int i = blockIdx.x * 256 + threadIdx.x;   // < 64*DI
  if (i >= 64 * DI) return;
  int r = i / DI, c = i % DI;
  const float* src = (r < 16) ? WA + (size_t)r * DI
                  : (r < 32) ? Wdt + (size_t)(r - 16) * DI
                  : (r < 48) ? WB + (size_t)(r - 32) * DI
                             : WC + (size_t)(r - 48) * DI;
  Wb[i] = f2b(src[c]);
  if (i < 64) bias64[i] = (i < 16) ? bA[i] : (i < 32) ? bdt[i - 16] : (i < 48) ? bB[i - 32] : bC[i - 48];
}

// ---------------- LayerNorm -> bf16 ----------------
__global__ __launch_bounds__(256) void ln_kernel(const float* __restrict__ x, const float* __restrict__ g,
                                                 const float* __restrict__ bb, u16* __restrict__ xn) {
  int m = blockIdx.x, tid = threadIdx.x;
  const float* xr = x + (size_t)m * DM;
  float v0 = xr[tid], v1 = xr[tid + 256], v2 = xr[tid + 512];
  float s  = v0 + v1 + v2;
  float s2 = fmaf(v0, v0, fmaf(v1, v1, v2 * v2));
  #pragma unroll
  for (int off = 32; off > 0; off >>= 1) { s += __shfl_down(s, off); s2 += __shfl_down(s2, off); }
  __shared__ float sh[8];
  int wave = tid >> 6, lane = tid & 63;
  if (lane == 0) { sh[wave] = s; sh[4 + wave] = s2; }
  __syncthreads();
  float S1 = sh[0] + sh[1] + sh[2] + sh[3];
  float S2 = sh[4] + sh[5] + sh[6] + sh[7];
  float mu = S1 * (1.f / DM);
  float var = S2 * (1.f / DM) - mu * mu;
  float rs = rsqrtf(var + 1e-5f);
  u16* o = xn + (size_t)m * DM;
  o[tid]       = f2b((v0 - mu) * rs * g[tid]       + bb[tid]);
  o[tid + 256] = f2b((v1 - mu) * rs * g[tid + 256] + bb[tid + 256]);
  o[tid + 512] = f2b((v2 - mu) * rs * g[tid + 512] + bb[tid + 512]);
}

__device__ __forceinline__ void gll16(const void* g, void* l) {
  __builtin_amdgcn_global_load_lds((const __attribute__((address_space(1))) void*)g,
                                   (__attribute__((address_space(3))) void*)l, 16, 0, 0);
}

// ---------------- bf16 MFMA NT-GEMM (128²): acc = A[M][K] * B[N][K]^T + bias ----------------
// 512 threads, 8 waves, 128x128 block tile, 32x64 wave tile, BK=32.
// Depth-4 pipeline: 5 LDS buffers (80KB, 2 blocks/CU), counted vmcnt(6); tail 6->4->2->0.
// MODE 0: C f32 = acc + bias + aux(resid, f32)
// MODE 1: Cb = bf16(b2f(auxb)*sigmoid(acc+bias))
// MODE 2: Cb = bf16(acc + bias)
template <int MODE>
__global__ __launch_bounds__(512) void gemm_bt(const u16* __restrict__ A, const u16* __restrict__ B,
                                               const float* __restrict__ bias, const float* __restrict__ aux,
                                               const u16* __restrict__ auxb,
                                               float* __restrict__ C, u16* __restrict__ Cb,
                                               int M, int N, int K) {
  __shared__ __align__(16) u16 As[5][128 * 32];
  __shared__ __align__(16) u16 Bs[5][128 * 32];
  const int tid = threadIdx.x, wave = tid >> 6, lane = tid & 63;

  // XCD-aware bijective swizzle (nwg % 8 == 0 for all our grids)
  const int nbx = gridDim.x, nwg = nbx * gridDim.y;
  const int orig = blockIdx.y * nbx + blockIdx.x;
  const int cpx = nwg >> 3;
  const int swz = (orig & 7) * cpx + (orig >> 3);
  const int m0 = (swz / nbx) * 128, n0 = (swz % nbx) * 128;

  const int wm = (wave >> 1) * 32, wn = (wave & 1) * 64;
  const int fr = lane & 15, fq = lane >> 4;
  f32x4 acc[2][4] = {};

  // staging: LDS chunk c (linear dest) holds global k-chunk (c&3)^((c>>3)&3) of row c>>2
  const int c0 = tid;   // 512 chunks of 16B cover 128x32
  const u16* Ag0 = A + (size_t)(m0 + (c0 >> 2)) * K + ((c0 & 3) ^ ((c0 >> 3) & 3)) * 8;
  const u16* Bg0 = B + (size_t)(n0 + (c0 >> 2)) * K + ((c0 & 3) ^ ((c0 >> 3) & 3)) * 8;
  const int lofs = (wave * 64) * 8;   // wave-uniform LDS base; HW adds lane*16B

  // swizzled ds_read offsets (u16 units), 2-way max per 8 bank-slots
  int offA[2], offB[4];
  #pragma unroll
  for (int i = 0; i < 2; ++i) {
    int ra = wm + i * 16 + fr;
    offA[i] = ra * 32 + (fq ^ ((ra >> 1) & 3)) * 8;
  }
  #pragma unroll
  for (int i = 0; i < 4; ++i) {
    int rb = wn + i * 16 + fr;
    offB[i] = rb * 32 + (fq ^ ((rb >> 1) & 3)) * 8;
  }

  const int nk = K >> 5;   // >= 24 for all our GEMMs

#define STAGE_BT(tt) { const int bb_ = (tt) % 5; \
                       gll16(Ag0 + (tt) * 32, (u16*)As[bb_] + lofs); \
                       gll16(Bg0 + (tt) * 32, (u16*)Bs[bb_] + lofs); }
#define COMPUTE_BT(tt) { const u16* as_ = As[(tt) % 5]; const u16* bs_ = Bs[(tt) % 5]; \
    short8 av[2], bv[4]; \
    _Pragma("unroll") for (int i = 0; i < 2; ++i) av[i] = *(const short8*)(as_ + offA[i]); \
    _Pragma("unroll") for (int i = 0; i < 4; ++i) bv[i] = *(const short8*)(bs_ + offB[i]); \
    __builtin_amdgcn_s_setprio(1); \
    _Pragma("unroll") for (int mi = 0; mi < 2; ++mi) \
      _Pragma("unroll") for (int ni = 0; ni < 4; ++ni) \
        acc[mi][ni] = __builtin_amdgcn_mfma_f32_16x16x32_bf16(av[mi], bv[ni], acc[mi][ni], 0, 0, 0); \
    __builtin_amdgcn_s_setprio(0); }

  STAGE_BT(0); STAGE_BT(1); STAGE_BT(2); STAGE_BT(3);   // 8 loads in flight per wave

  for (int t = 0; t < nk - 4; ++t) {
    asm volatile("s_waitcnt vmcnt(6)" ::: "memory");   // tile t arrived; t+1..t+3 in flight
    __builtin_amdgcn_s_barrier();
    STAGE_BT(t + 4);            // buf (t+4)%5 == (t-1)%5: its readers passed this barrier
    COMPUTE_BT(t);
  }
  asm volatile("s_waitcnt vmcnt(6)" ::: "memory");
  __builtin_amdgcn_s_barrier();
  COMPUTE_BT(nk - 4);
  asm volatile("s_waitcnt vmcnt(4)" ::: "memory");
  __builtin_amdgcn_s_barrier();
  COMPUTE_BT(nk - 3);
  asm volatile("s_waitcnt vmcnt(2)" ::: "memory");
  __builtin_amdgcn_s_barrier();
  COMPUTE_BT(nk - 2);
  asm volatile("s_waitcnt vmcnt(0)" ::: "memory");
  __builtin_amdgcn_s_barrier();
  COMPUTE_BT(nk - 1);
#undef STAGE_BT
#undef COMPUTE_BT

  #pragma unroll
  for (int ni = 0; ni < 4; ++ni) {
    int col = n0 + wn + ni * 16 + fr;
    float bv_ = bias[col];
    #pragma unroll
    for (int mi = 0; mi < 2; ++mi) {
      int row = m0 + wm + mi * 16 + fq * 4;
      #pragma unroll
      for (int j = 0; j < 4; ++j) {
        size_t off = (size_t)(row + j) * N + col;
        float z = acc[mi][ni][j] + bv_;
        if (MODE == 0) {
          C[off] = z + aux[off];
        } else if (MODE == 1) {
          Cb[off] = f2b(b2f(auxb[off]) * sigmoidf_(z));
        } else {
          Cb[off] = f2b(z);
        }
      }
    }
  }
}

// ---------------- abcd GEMM split-K: Zp[ks] = ub[M][Kq] * Wabcd[64][Kq]^T ----------------
__global__ __launch_bounds__(256) void gemm_abcd(const u16* __restrict__ A, const u16* __restrict__ B,
                                                 float* __restrict__ Zp, int M, int K) {
  __shared__ __align__(16) u16 As[2][64 * 64];
  __shared__ __align__(16) u16 Bs[2][64 * 64];
  const int tid = threadIdx.x, wave = tid >> 6, lane = tid & 63;
  const int m0 = blockIdx.x * 64;
  const int ks = blockIdx.y;
  const int Kq = K >> 2;            // 384
  const int kbase = ks * Kq;
  const int wm = wave * 16;
  const int fr = lane & 15, fq = lane >> 4;
  f32x4 acc[4] = {};

  const int c0 = tid, c1 = tid + 256;
  const u16* Ag0 = A + (size_t)(m0 + (c0 >> 3)) * K + kbase + ((c0 & 7) ^ ((c0 >> 3) & 7)) * 8;
  const u16* Ag1 = A + (size_t)(m0 + (c1 >> 3)) * K + kbase + ((c1 & 7) ^ ((c1 >> 3) & 7)) * 8;
  const u16* Bg0 = B + (size_t)(c0 >> 3) * K + kbase + ((c0 & 7) ^ ((c0 >> 3) & 7)) * 8;
  const u16* Bg1 = B + (size_t)(c1 >> 3) * K + kbase + ((c1 & 7) ^ ((c1 >> 3) & 7)) * 8;
  const int lo0 = (wave * 64) * 8;
  const int lo1 = (256 + wave * 64) * 8;

  int offAv[2], offBv[2][4];
  {
    int r = wm + fr;
    #pragma unroll
    for (int kk = 0; kk < 2; ++kk) offAv[kk] = r * 64 + ((kk * 4 + fq) ^ (r & 7)) * 8;
    #pragma unroll
    for (int i = 0; i < 4; ++i) {
      int rb = i * 16 + fr;
      #pragma unroll
      for (int kk = 0; kk < 2; ++kk) offBv[kk][i] = rb * 64 + ((kk * 4 + fq) ^ (rb & 7)) * 8;
    }
  }

  const int nk = Kq >> 6;   // 6
  gll16(Ag0, (u16*)As[0] + lo0);
  gll16(Ag1, (u16*)As[0] + lo1);
  gll16(Bg0, (u16*)Bs[0] + lo0);
  gll16(Bg1, (u16*)Bs[0] + lo1);

  for (int t = 0; t < nk; ++t) {
    __syncthreads();
    if (t + 1 < nk) {
      int ko = (t + 1) * 64;
      gll16(Ag0 + ko, (u16*)As[(t + 1) & 1] + lo0);
      gll16(Ag1 + ko, (u16*)As[(t + 1) & 1] + lo1);
      gll16(Bg0 + ko, (u16*)Bs[(t + 1) & 1] + lo0);
      gll16(Bg1 + ko, (u16*)Bs[(t + 1) & 1] + lo1);
    }
    const u16* as = As[t & 1];
    const u16* bs = Bs[t & 1];
    #pragma unroll
    for (int kk = 0; kk < 2; ++kk) {
      short8 av = *(const short8*)(as + offAv[kk]);
      short8 bv[4];
      #pragma unroll
      for (int i = 0; i < 4; ++i) bv[i] = *(const short8*)(bs + offBv[kk][i]);
      #pragma unroll
      for (int ni = 0; ni < 4; ++ni)
        acc[ni] = __builtin_amdgcn_mfma_f32_16x16x32_bf16(av, bv[ni], acc[ni], 0, 0, 0);
    }
  }

  float* zp = Zp + (size_t)ks * M * 64;
  #pragma unroll
  for (int ni = 0; ni < 4; ++ni) {
    int col = ni * 16 + fr;
    #pragma unroll
    for (int j = 0; j < 4; ++j) {
      int row = m0 + wm + fq * 4 + j;
      zp[(size_t)row * 64 + col] = acc[ni][j];
    }
  }
}

// combine split-K partials; fused dec/Bm/Cm epilogue
__global__ __launch_bounds__(256) void abcd_combine(const float* __restrict__ Zp, const float* __restrict__ bias64,
                                                    float* __restrict__ dec, float* __restrict__ Bm,
                                                    float* __restrict__ Cm, int M) {
  int idx = blockIdx.x * 256 + threadIdx.x;  // < M*16
  int row = idx >> 4, n = idx & 15;
  float zA = bias64[n], zDt = bias64[16 + n], zB = bias64[32 + n], zC = bias64[48 + n];
  #pragma unroll
  for (int ks = 0; ks < 4; ++ks) {
    const float* zp = Zp + ((size_t)ks * M + row) * 64;
    zA += zp[n]; zDt += zp[16 + n]; zB += zp[32 + n]; zC += zp[48 + n];
  }
  size_t o = (size_t)row * NST + n;
  dec[o] = expf(-expf(zA + zDt));
  Bm[o] = zB;
  Cm[o] = zC;
}

// ---------------- depthwise causal conv (k=4) + bias + silu; short8-vectorized ----------------
__global__ __launch_bounds__(256) void conv_silu(const u16* __restrict__ xpg, const float* __restrict__ cw,
                                                 const float* __restrict__ cb, u16* __restrict__ xab) {
  int idx = blockIdx.x * 256 + threadIdx.x;   // < NTOK*DI/8
  int d8 = idx % (DI / 8);
  int token = idx / (DI / 8);
  int t = token % SEQ;
  int d0 = d8 * 8;
  const short8* xv = (const short8*)(xpg + (size_t)token * NIG + d0);
  short8 z8 = {0, 0, 0, 0, 0, 0, 0, 0};
  short8 x3 = (t >= 3) ? xv[-3 * (NIG / 8)] : z8;
  short8 x2 = (t >= 2) ? xv[-2 * (NIG / 8)] : z8;
  short8 x1 = (t >= 1) ? xv[-1 * (NIG / 8)] : z8;
  short8 x0 = xv[0];
  const float4* cw4 = (const float4*)cw;
  float4 cbl = ((const float4*)cb)[d8 * 2], cbh = ((const float4*)cb)[d8 * 2 + 1];
  float cbv[8] = {cbl.x, cbl.y, cbl.z, cbl.w, cbh.x, cbh.y, cbh.z, cbh.w};
  short8 o;
  #pragma unroll
  for (int j = 0; j < 8; ++j) {
    float4 w = cw4[d0 + j];
    float a = cbv[j];
    a = fmaf(b2f((u16)x3[j]), w.x, a);
    a = fmaf(b2f((u16)x2[j]), w.y, a);
    a = fmaf(b2f((u16)x1[j]), w.z, a);
    a = fmaf(b2f((u16)x0[j]), w.w, a);
    o[j] = (short)f2b(siluf_(a));
  }
  *(short8*)(xab + (size_t)token * DI + d0) = o;
}

// ---------------- chunked selective scan ----------------
__global__ __launch_bounds__(256) void scan_phase1(const u16* __restrict__ ub, const float* __restrict__ dec,
                                                   const float* __restrict__ Bm, float* __restrict__ lend,
                                                   float* __restrict__ P) {
  __shared__ float dl[LCH * NST], bl[LCH * NST];
  int bid = blockIdx.x;
  int dblk = bid % 6, b = (bid / 6) % BATCH, c = bid / (6 * BATCH);
  int d = dblk * 256 + threadIdx.x;
  int t0 = c * LCH;
  size_t base16 = (size_t)(b * SEQ + t0) * NST;
  for (int i = threadIdx.x; i < LCH * NST; i += 256) { dl[i] = dec[base16 + i]; bl[i] = Bm[base16 + i]; }
  __syncthreads();
  float h[NST];
  #pragma unroll
  for (int n = 0; n < NST; ++n) h[n] = 0.f;
  const u16* up = ub + (size_t)(b * SEQ + t0) * DI + d;
  for (int t = 0; t < LCH; ++t) {
    float uu = b2f(up[(size_t)t * DI]);
    #pragma unroll
    for (int n = 0; n < NST; ++n) h[n] = fmaf(h[n], dl[t * NST + n], bl[t * NST + n] * uu);
  }
  float* lo = lend + ((size_t)(c * BATCH + b) * DI + d) * NST;
  ((float4*)lo)[0] = make_float4(h[0], h[1], h[2], h[3]);
  ((float4*)lo)[1] = make_float4(h[4], h[5], h[6], h[7]);
  ((float4*)lo)[2] = make_float4(h[8], h[9], h[10], h[11]);
  ((float4*)lo)[3] = make_float4(h[12], h[13], h[14], h[15]);
  if (dblk == 0 && threadIdx.x < NST) {
    float pr = 1.f;
    for (int t = 0; t < LCH; ++t) pr *= dl[t * NST + threadIdx.x];
    P[(size_t)(c * BATCH + b) * NST + threadIdx.x] = pr;
  }
}

__global__ __launch_bounds__(256) void scan_phase2(const float* __restrict__ lend, const float* __restrict__ P,
                                                   float* __restrict__ Hin) {
  int flat = blockIdx.x * 256 + threadIdx.x;  // < BATCH*DI*NST
  int n = flat & 15;
  int d = (flat >> 4) % DI;
  int b = flat / (DI * NST);
  float h = 0.f;
  for (int c = 0; c < NCH; ++c) {
    size_t idx = ((size_t)(c * BATCH + b) * DI + d) * NST + n;
    Hin[idx] = h;
    h = fmaf(P[(size_t)(c * BATCH + b) * NST + n], h, lend[idx]);
  }
}

__global__ __launch_bounds__(256) void scan_phase3(const u16* __restrict__ ub, const float* __restrict__ dec,
                                                   const float* __restrict__ Bm, const float* __restrict__ Cm,
                                                   const float* __restrict__ Hin, const u16* __restrict__ xpg,
                                                   u16* __restrict__ gy) {
  __shared__ float dl[LCH * NST], bl[LCH * NST], cl[LCH * NST];
  int bid = blockIdx.x;
  int dblk = bid % 6, b = (bid / 6) % BATCH, c = bid / (6 * BATCH);
  int d = dblk * 256 + threadIdx.x;
  int t0 = c * LCH;
  size_t base16 = (size_t)(b * SEQ + t0) * NST;
  for (int i = threadIdx.x; i < LCH * NST; i += 256) {
    dl[i] = dec[base16 + i]; bl[i] = Bm[base16 + i]; cl[i] = Cm[base16 + i];
  }
  __syncthreads();
  float h[NST];
  const float4* hi = (const float4*)(Hin + ((size_t)(c * BATCH + b) * DI + d) * NST);
  float4 h0 = hi[0], h1 = hi[1], h2 = hi[2], h3 = hi[3];
  h[0]=h0.x; h[1]=h0.y; h[2]=h0.z; h[3]=h0.w; h[4]=h1.x; h[5]=h1.y; h[6]=h1.z; h[7]=h1.w;
  h[8]=h2.x; h[9]=h2.y; h[10]=h2.z; h[11]=h2.w; h[12]=h3.x; h[13]=h3.y; h[14]=h3.z; h[15]=h3.w;
  const u16* up = ub + (size_t)(b * SEQ + t0) * DI + d;
  const u16* gp = xpg + (size_t)(b * SEQ + t0) * NIG + DI + d;
  u16* yp = gy + (size_t)(b * SEQ + t0) * DI + d;
  for (int t = 0; t < LCH; ++t) {
    float uu = b2f(up[(size_t)t * DI]);
    float acc = 0.f;
    #pragma unroll
    for (int n = 0; n < NST; ++n) {
      h[n] = fmaf(h[n], dl[t * NST + n], bl[t * NST + n] * uu);
      acc = fmaf(h[n], cl[t * NST + n], acc);
    }
    float g = b2f(gp[(size_t)t * NIG]);
    yp[(size_t)t * DI] = f2b(siluf_(g) * acc);
  }
}

extern "C" void kernel_launch(void* const* d_in, const int* in_sizes, int n_in,
                              void* d_out, int out_size, void* d_ws, size_t ws_size,
                              hipStream_t stream) {
  const float* x      = (const float*)d_in[0];
  const float* ln_g   = (const float*)d_in[1];
  const float* ln_b   = (const float*)d_in[2];
  const float* W_in   = (const float*)d_in[3];
  const float* b_in   = (const float*)d_in[4];
  const float* conv_w = (const float*)d_in[5];
  const float* conv_b = (const float*)d_in[6];
  const float* W_A    = (const float*)d_in[7];
  const float* b_A    = (const float*)d_in[8];
  const float* W_B    = (const float*)d_in[9];
  const float* b_B    = (const float*)d_in[10];
  const float* W_C    = (const float*)d_in[11];
  const float* b_C    = (const float*)d_in[12];
  const float* W_dt   = (const float*)d_in[13];
  const float* b_dt   = (const float*)d_in[14];
  const float* W_S    = (const float*)d_in[15];
  const float* b_S    = (const float*)d_in[16];
  const float* W_gate = (const float*)d_in[17];
  const float* b_gate = (const float*)d_in[18];
  const float* W_out  = (const float*)d_in[19];
  const float* b_out  = (const float*)d_in[20];
  float* out = (float*)d_out;

  char* p = (char*)d_ws;
  auto alloc = [&](size_t bytes) { char* r = p; p += (bytes + 255) & ~(size_t)255; return r; };
  u16*   Wigb    = (u16*)alloc((size_t)NIG * DM * 2);   // [3072][768] = W_in | W_gate
  float* biasig  = (float*)alloc((size_t)NIG * 4);
  u16*   WSb     = (u16*)alloc((size_t)DI * DI * 2);    // first half of W_S only
  u16*   Woutb   = (u16*)alloc((size_t)DM * DI * 2);
  u16*   Wabcd   = (u16*)alloc((size_t)64 * DI * 2);
  float* bias64  = (float*)alloc(64 * 4);
  u16*   xnb     = (u16*)alloc((size_t)NTOK * DM * 2);
  u16*   xpg     = (u16*)alloc((size_t)NTOK * NIG * 2); // [tok][3072]: xp | gate (bf16)
  u16*   xab     = (u16*)alloc((size_t)NTOK * DI * 2);  // silu(conv) bf16; reused as gy
  u16*   ub      = (u16*)alloc((size_t)NTOK * DI * 2);  // u bf16
  float* Zp      = (float*)alloc((size_t)4 * NTOK * 64 * 4);  // split-K partials
  float* decb    = (float*)alloc((size_t)NTOK * NST * 4);
  float* Bmb     = (float*)alloc((size_t)NTOK * NST * 4);
  float* Cmb     = (float*)alloc((size_t)NTOK * NST * 4);
  float* lend    = (float*)alloc((size_t)NCH * BATCH * DI * NST * 4);
  float* Hin     = (float*)alloc((size_t)NCH * BATCH * DI * NST * 4);
  float* P       = (float*)alloc((size_t)NCH * BATCH * NST * 4);
  u16* gy = xab;

  // weight prep
  cast_ingate<<<(NIG * DM + 255) / 256, 256, 0, stream>>>(W_in, W_gate, b_in, b_gate, Wigb, biasig);
  cast_two<<<(DI * DI / 4 + DM * DI / 4 + 255) / 256, 256, 0, stream>>>(W_S, WSb, DI * DI / 4,
                                                                        W_out, Woutb, DM * DI / 4);
  cast_wabcd<<<(64 * DI + 255) / 256, 256, 0, stream>>>(W_A, W_dt, W_B, W_C, b_A, b_dt, b_B, b_C, Wabcd, bias64);

  ln_kernel<<<NTOK, 256, 0, stream>>>(x, ln_g, ln_b, xnb);

  // fused in|gate GEMM -> xpg bf16
  gemm_bt<2><<<dim3(NIG / 128, NTOK / 128), 512, 0, stream>>>(xnb, Wigb, biasig, nullptr, nullptr,
                                                              nullptr, xpg, NTOK, NIG, DM);

  conv_silu<<<NTOK * (DI / 8) / 256, 256, 0, stream>>>(xpg, conv_w, conv_b, xab);

  // S GEMM with fused u = xa * sigmoid(Sp) -> ub bf16 (aux = xab, same buffer as A operand)
  gemm_bt<1><<<dim3(DI / 128, NTOK / 128), 512, 0, stream>>>(xab, WSb, b_S, nullptr, xab,
                                                             nullptr, ub, NTOK, DI, DI);

  gemm_abcd<<<dim3(NTOK / 64, 4), 256, 0, stream>>>(ub, Wabcd, Zp, NTOK, DI);
  abcd_combine<<<NTOK * 16 / 256, 256, 0, stream>>>(Zp, bias64, decb, Bmb, Cmb, NTOK);

  scan_phase1<<<NCH * BATCH * (DI / 256), 256, 0, stream>>>(ub, decb, Bmb, lend, P);
  scan_phase2<<<BATCH * DI * NST / 256, 256, 0, stream>>>(lend, P, Hin);
  scan_phase3<<<NCH * BATCH * (DI / 256), 256, 0, stream>>>(ub, decb, Bmb, Cmb, Hin, xpg, gy);

  // out GEMM + residual (f32 out)
  gemm_bt<0><<<dim3(DM / 128, NTOK / 128), 512, 0, stream>>>(gy, Woutb, b_out, x, nullptr,
                                                             out, nullptr, NTOK, DM, DI);
}

// Round 13
// 200.269 us; speedup vs baseline: 1.0813x; 1.0335x over previous
//
#include <hip/hip_runtime.h>

// BayesianMambaBlock on MI355X (gfx950).
// LN -> fused (in|gate) GEMM -> conv+silu -> S GEMM (fused u) -> abcd GEMM split-K4 + combine ->
// chunked scan (bf16 state, phase3 fused gate) -> out GEMM [BM=64 variant] (+resid, f32).
// gemm_bt<MODE,BM>: BM=128: 512 thr/8 waves; BM=64: 256 thr/4 waves. 128(or 64)x128 tile, 32x64 wave
// tile, BK=32, depth-3 pipeline (4 LDS buffers), counted vmcnt + raw s_barrier, setprio,
// chunk-XOR LDS swizzle, XCD-aware block swizzle.

typedef unsigned short u16;
using short8 = __attribute__((ext_vector_type(8))) short;
using f32x4  = __attribute__((ext_vector_type(4))) float;

#define BATCH 2
#define SEQ   2048
#define DM    768
#define DI    1536
#define NIG   (2*DI)        // fused in+gate width 3072
#define NST   16
#define LCH   64
#define NCH   32
#define NTOK  (BATCH*SEQ)   // 4096

__device__ __forceinline__ u16 f2b(float x) {
  unsigned u = __float_as_uint(x);
  u += 0x7FFFu + ((u >> 16) & 1u);   // round-to-nearest-even bf16
  return (u16)(u >> 16);
}
__device__ __forceinline__ float b2f(u16 v) { return __uint_as_float((unsigned)v << 16); }
__device__ __forceinline__ float sigmoidf_(float x) { return 1.f / (1.f + expf(-x)); }
__device__ __forceinline__ float siluf_(float x) { return x / (1.f + expf(-x)); }

// ---------------- one-shot weight prep: all casts in a single launch ----------------
#define N_IG   (NIG * DM / 4)
#define N_WS   (DI * DI / 4)
#define N_WO   (DM * DI / 4)
#define N_WAB  (64 * DI / 4)
#define N_CAST (N_IG + N_WS + N_WO + N_WAB + NIG + 64)

__global__ __launch_bounds__(256) void cast_all(
    const float* __restrict__ Wi, const float* __restrict__ Wg,
    const float* __restrict__ bi, const float* __restrict__ bg,
    const float* __restrict__ WS, const float* __restrict__ WO,
    const float* __restrict__ WA, const float* __restrict__ Wdt,
    const float* __restrict__ WB, const float* __restrict__ WC,
    const float* __restrict__ bA, const float* __restrict__ bdt,
    const float* __restrict__ bB, const float* __restrict__ bC,
    u16* __restrict__ Wigb, float* __restrict__ biasig,
    u16* __restrict__ WSb, u16* __restrict__ Woutb,
    u16* __restrict__ Wabcd, float* __restrict__ bias64) {
  int i = blockIdx.x * 256 + threadIdx.x;
  if (i < N_IG) {
    int i4 = i * 4, r = i4 / DM, c = i4 % DM;
    const float* src = (r < DI) ? Wi + (size_t)r * DM + c : Wg + (size_t)(r - DI) * DM + c;
    float4 v = *(const float4*)src;
    ushort4 o; o.x = f2b(v.x); o.y = f2b(v.y); o.z = f2b(v.z); o.w = f2b(v.w);
    ((ushort4*)Wigb)[i] = o;
  } else if (i < N_IG + N_WS) {
    int j = i - N_IG;
    float4 v = ((const float4*)WS)[j];
    ushort4 o; o.x = f2b(v.x); o.y = f2b(v.y); o.z = f2b(v.z); o.w = f2b(v.w);
    ((ushort4*)WSb)[j] = o;
  } else if (i < N_IG + N_WS + N_WO) {
    int j = i - N_IG - N_WS;
    float4 v = ((const float4*)WO)[j];
    ushort4 o; o.x = f2b(v.x); o.y = f2b(v.y); o.z = f2b(v.z); o.w = f2b(v.w);
    ((ushort4*)Woutb)[j] = o;
  } else if (i < N_IG + N_WS + N_WO + N_WAB) {
    int j = i - N_IG - N_WS - N_WO;
    int i4 = j * 4, r = i4 / DI, c = i4 % DI;
    const float* src = (r < 16) ? WA + (size_t)r * DI
                     : (r < 32) ? Wdt + (size_t)(r - 16) * DI
                     : (r < 48) ? WB + (size_t)(r - 32) * DI
                                : WC + (size_t)(r - 48) * DI;
    float4 v = *(const float4*)(src + c);
    ushort4 o; o.x = f2b(v.x); o.y = f2b(v.y); o.z = f2b(v.z); o.w = f2b(v.w);
    ((ushort4*)Wabcd)[j] = o;
  } else if (i < N_IG + N_WS + N_WO + N_WAB + NIG) {
    int j = i - N_IG - N_WS - N_WO - N_WAB;
    biasig[j] = (j < DI) ? bi[j] : bg[j - DI];
  } else if (i < N_CAST) {
    int j = i - N_IG - N_WS - N_WO - N_WAB - NIG;
    bias64[j] = (j < 16) ? bA[j] : (j < 32) ? bdt[j - 16] : (j < 48) ? bB[j - 32] : bC[j - 48];
  }
}

// ---------------- LayerNorm -> bf16 ----------------
__global__ __launch_bounds__(256) void ln_kernel(const float* __restrict__ x, const float* __restrict__ g,
                                                 const float* __restrict__ bb, u16* __restrict__ xn) {
  int m = blockIdx.x, tid = threadIdx.x;
  const float* xr = x + (size_t)m * DM;
  float v0 = xr[tid], v1 = xr[tid + 256], v2 = xr[tid + 512];
  float s  = v0 + v1 + v2;
  float s2 = fmaf(v0, v0, fmaf(v1, v1, v2 * v2));
  #pragma unroll
  for (int off = 32; off > 0; off >>= 1) { s += __shfl_down(s, off); s2 += __shfl_down(s2, off); }
  __shared__ float sh[8];
  int wave = tid >> 6, lane = tid & 63;
  if (lane == 0) { sh[wave] = s; sh[4 + wave] = s2; }
  __syncthreads();
  float S1 = sh[0] + sh[1] + sh[2] + sh[3];
  float S2 = sh[4] + sh[5] + sh[6] + sh[7];
  float mu = S1 * (1.f / DM);
  float var = S2 * (1.f / DM) - mu * mu;
  float rs = rsqrtf(var + 1e-5f);
  u16* o = xn + (size_t)m * DM;
  o[tid]       = f2b((v0 - mu) * rs * g[tid]       + bb[tid]);
  o[tid + 256] = f2b((v1 - mu) * rs * g[tid + 256] + bb[tid + 256]);
  o[tid + 512] = f2b((v2 - mu) * rs * g[tid + 512] + bb[tid + 512]);
}

__device__ __forceinline__ void gll16(const void* g, void* l) {
  __builtin_amdgcn_global_load_lds((const __attribute__((address_space(1))) void*)g,
                                   (__attribute__((address_space(3))) void*)l, 16, 0, 0);
}

// ---------------- bf16 MFMA NT-GEMM: acc = A[M][K] * B[N][K]^T + bias ----------------
// BM=128: 512 thr/8 waves; BM=64: 256 thr/4 waves. Tile BMx128, wave tile 32x64, BK=32.
// Depth-3 pipeline: 4 LDS buffers, counted vmcnt (S loads/stage: wait 2S / S / 0).
// MODE 0: C f32 = acc + bias + aux(resid f32); MODE 1: Cb = bf16(b2f(auxb)*sigmoid(acc+bias));
// MODE 2: Cb = bf16(acc+bias)
template <int MODE, int BM>
__global__ __launch_bounds__(BM == 128 ? 512 : 256) void gemm_bt(
    const u16* __restrict__ A, const u16* __restrict__ B,
    const float* __restrict__ bias, const float* __restrict__ aux,
    const u16* __restrict__ auxb,
    float* __restrict__ C, u16* __restrict__ Cb,
    int M, int N, int K) {
  __shared__ __align__(16) u16 As[4][BM * 32];
  __shared__ __align__(16) u16 Bs[4][128 * 32];
  const int tid = threadIdx.x, wave = tid >> 6, lane = tid & 63;

  // XCD-aware bijective swizzle (nwg % 8 == 0 for all our grids)
  const int nbx = gridDim.x, nwg = nbx * gridDim.y;
  const int orig = blockIdx.y * nbx + blockIdx.x;
  const int cpx = nwg >> 3;
  const int swz = (orig & 7) * cpx + (orig >> 3);
  const int m0 = (swz / nbx) * BM, n0 = (swz % nbx) * 128;

  const int wm = (wave >> 1) * 32, wn = (wave & 1) * 64;
  const int fr = lane & 15, fq = lane >> 4;
  f32x4 acc[2][4] = {};

  // staging: LDS chunk c (linear dest) holds global k-chunk (c&3)^((c>>3)&3) of row c>>2
  const int c0 = tid;
  const u16* Ag0 = A + (size_t)(m0 + (c0 >> 2)) * K + ((c0 & 3) ^ ((c0 >> 3) & 3)) * 8;
  const u16* Bg0 = B + (size_t)(n0 + (c0 >> 2)) * K + ((c0 & 3) ^ ((c0 >> 3) & 3)) * 8;
  const int lofs = (wave * 64) * 8;   // wave-uniform base; HW adds lane*16B
  // BM==64 only: second B chunk
  const int c1 = tid + 256;
  const u16* Bg1 = B + (size_t)(n0 + (c1 >> 2)) * K + ((c1 & 3) ^ ((c1 >> 3) & 3)) * 8;
  const int lofs1 = (256 + wave * 64) * 8;

  int offA[2], offB[4];
  #pragma unroll
  for (int i = 0; i < 2; ++i) {
    int ra = wm + i * 16 + fr;
    offA[i] = ra * 32 + (fq ^ ((ra >> 1) & 3)) * 8;
  }
  #pragma unroll
  for (int i = 0; i < 4; ++i) {
    int rb = wn + i * 16 + fr;
    offB[i] = rb * 32 + (fq ^ ((rb >> 1) & 3)) * 8;
  }

  const int nk = K >> 5;

#define STAGE_BT(tt) { gll16(Ag0 + (tt) * 32, (u16*)As[(tt) & 3] + lofs); \
                       gll16(Bg0 + (tt) * 32, (u16*)Bs[(tt) & 3] + lofs); \
                       if (BM == 64) gll16(Bg1 + (tt) * 32, (u16*)Bs[(tt) & 3] + lofs1); }
#define COMPUTE_BT(tt) { const u16* as_ = As[(tt) & 3]; const u16* bs_ = Bs[(tt) & 3]; \
    short8 av[2], bv[4]; \
    _Pragma("unroll") for (int i = 0; i < 2; ++i) av[i] = *(const short8*)(as_ + offA[i]); \
    _Pragma("unroll") for (int i = 0; i < 4; ++i) bv[i] = *(const short8*)(bs_ + offB[i]); \
    __builtin_amdgcn_s_setprio(1); \
    _Pragma("unroll") for (int mi = 0; mi < 2; ++mi) \
      _Pragma("unroll") for (int ni = 0; ni < 4; ++ni) \
        acc[mi][ni] = __builtin_amdgcn_mfma_f32_16x16x32_bf16(av[mi], bv[ni], acc[mi][ni], 0, 0, 0); \
    __builtin_amdgcn_s_setprio(0); }
#define WAIT2S() { if (BM == 128) asm volatile("s_waitcnt vmcnt(4)" ::: "memory"); \
                   else           asm volatile("s_waitcnt vmcnt(6)" ::: "memory"); }
#define WAIT1S() { if (BM == 128) asm volatile("s_waitcnt vmcnt(2)" ::: "memory"); \
                   else           asm volatile("s_waitcnt vmcnt(3)" ::: "memory"); }

  STAGE_BT(0); STAGE_BT(1); STAGE_BT(2);

  for (int t = 0; t < nk - 3; ++t) {
    WAIT2S();                       // tile t arrived; t+1,t+2 in flight
    __builtin_amdgcn_s_barrier();
    STAGE_BT(t + 3);                // buf (t+3)&3 == (t-1)&3: its readers passed this barrier
    COMPUTE_BT(t);
  }
  WAIT2S();
  __builtin_amdgcn_s_barrier();
  COMPUTE_BT(nk - 3);
  WAIT1S();
  __builtin_amdgcn_s_barrier();
  COMPUTE_BT(nk - 2);
  asm volatile("s_waitcnt vmcnt(0)" ::: "memory");
  __builtin_amdgcn_s_barrier();
  COMPUTE_BT(nk - 1);
#undef STAGE_BT
#undef COMPUTE_BT
#undef WAIT2S
#undef WAIT1S

  #pragma unroll
  for (int ni = 0; ni < 4; ++ni) {
    int col = n0 + wn + ni * 16 + fr;
    float bv_ = bias[col];
    #pragma unroll
    for (int mi = 0; mi < 2; ++mi) {
      int row = m0 + wm + mi * 16 + fq * 4;
      #pragma unroll
      for (int j = 0; j < 4; ++j) {
        size_t off = (size_t)(row + j) * N + col;
        float z = acc[mi][ni][j] + bv_;
        if (MODE == 0) {
          C[off] = z + aux[off];
        } else if (MODE == 1) {
          Cb[off] = f2b(b2f(auxb[off]) * sigmoidf_(z));
        } else {
          Cb[off] = f2b(z);
        }
      }
    }
  }
}

// ---------------- abcd GEMM split-K: Zp[ks] = ub[M][Kq] * Wabcd[64][Kq]^T ----------------
__global__ __launch_bounds__(256) void gemm_abcd(const u16* __restrict__ A, const u16* __restrict__ B,
                                                 float* __restrict__ Zp, int M, int K) {
  __shared__ __align__(16) u16 As[2][64 * 64];
  __shared__ __align__(16) u16 Bs[2][64 * 64];
  const int tid = threadIdx.x, wave = tid >> 6, lane = tid & 63;
  const int m0 = blockIdx.x * 64;
  const int ks = blockIdx.y;
  const int Kq = K >> 2;            // 384
  const int kbase = ks * Kq;
  const int wm = wave * 16;
  const int fr = lane & 15, fq = lane >> 4;
  f32x4 acc[4] = {};

  const int c0 = tid, c1 = tid + 256;
  const u16* Ag0 = A + (size_t)(m0 + (c0 >> 3)) * K + kbase + ((c0 & 7) ^ ((c0 >> 3) & 7)) * 8;
  const u16* Ag1 = A + (size_t)(m0 + (c1 >> 3)) * K + kbase + ((c1 & 7) ^ ((c1 >> 3) & 7)) * 8;
  const u16* Bg0 = B + (size_t)(c0 >> 3) * K + kbase + ((c0 & 7) ^ ((c0 >> 3) & 7)) * 8;
  const u16* Bg1 = B + (size_t)(c1 >> 3) * K + kbase + ((c1 & 7) ^ ((c1 >> 3) & 7)) * 8;
  const int lo0 = (wave * 64) * 8;
  const int lo1 = (256 + wave * 64) * 8;

  int offAv[2], offBv[2][4];
  {
    int r = wm + fr;
    #pragma unroll
    for (int kk = 0; kk < 2; ++kk) offAv[kk] = r * 64 + ((kk * 4 + fq) ^ (r & 7)) * 8;
    #pragma unroll
    for (int i = 0; i < 4; ++i) {
      int rb = i * 16 + fr;
      #pragma unroll
      for (int kk = 0; kk < 2; ++kk) offBv[kk][i] = rb * 64 + ((kk * 4 + fq) ^ (rb & 7)) * 8;
    }
  }

  const int nk = Kq >> 6;   // 6
  gll16(Ag0, (u16*)As[0] + lo0);
  gll16(Ag1, (u16*)As[0] + lo1);
  gll16(Bg0, (u16*)Bs[0] + lo0);
  gll16(Bg1, (u16*)Bs[0] + lo1);

  for (int t = 0; t < nk; ++t) {
    __syncthreads();
    if (t + 1 < nk) {
      int ko = (t + 1) * 64;
      gll16(Ag0 + ko, (u16*)As[(t + 1) & 1] + lo0);
      gll16(Ag1 + ko, (u16*)As[(t + 1) & 1] + lo1);
      gll16(Bg0 + ko, (u16*)Bs[(t + 1) & 1] + lo0);
      gll16(Bg1 + ko, (u16*)Bs[(t + 1) & 1] + lo1);
    }
    const u16* as = As[t & 1];
    const u16* bs = Bs[t & 1];
    #pragma unroll
    for (int kk = 0; kk < 2; ++kk) {
      short8 av = *(const short8*)(as + offAv[kk]);
      short8 bv[4];
      #pragma unroll
      for (int i = 0; i < 4; ++i) bv[i] = *(const short8*)(bs + offBv[kk][i]);
      #pragma unroll
      for (int ni = 0; ni < 4; ++ni)
        acc[ni] = __builtin_amdgcn_mfma_f32_16x16x32_bf16(av, bv[ni], acc[ni], 0, 0, 0);
    }
  }

  float* zp = Zp + (size_t)ks * M * 64;
  #pragma unroll
  for (int ni = 0; ni < 4; ++ni) {
    int col = ni * 16 + fr;
    #pragma unroll
    for (int j = 0; j < 4; ++j) {
      int row = m0 + wm + fq * 4 + j;
      zp[(size_t)row * 64 + col] = acc[ni][j];
    }
  }
}

// combine split-K partials; fused dec/Bm/Cm epilogue
__global__ __launch_bounds__(256) void abcd_combine(const float* __restrict__ Zp, const float* __restrict__ bias64,
                                                    float* __restrict__ dec, float* __restrict__ Bm,
                                                    float* __restrict__ Cm, int M) {
  int idx = blockIdx.x * 256 + threadIdx.x;  // < M*16
  int row = idx >> 4, n = idx & 15;
  float zA = bias64[n], zDt = bias64[16 + n], zB = bias64[32 + n], zC = bias64[48 + n];
  #pragma unroll
  for (int ks = 0; ks < 4; ++ks) {
    const float* zp = Zp + ((size_t)ks * M + row) * 64;
    zA += zp[n]; zDt += zp[16 + n]; zB += zp[32 + n]; zC += zp[48 + n];
  }
  size_t o = (size_t)row * NST + n;
  dec[o] = expf(-expf(zA + zDt));
  Bm[o] = zB;
  Cm[o] = zC;
}

// ---------------- depthwise causal conv (k=4) + bias + silu; short8-vectorized ----------------
__global__ __launch_bounds__(256) void conv_silu(const u16* __restrict__ xpg, const float* __restrict__ cw,
                                                 const float* __restrict__ cb, u16* __restrict__ xab) {
  int idx = blockIdx.x * 256 + threadIdx.x;   // < NTOK*DI/8
  int d8 = idx % (DI / 8);
  int token = idx / (DI / 8);
  int t = token % SEQ;
  int d0 = d8 * 8;
  const short8* xv = (const short8*)(xpg + (size_t)token * NIG + d0);
  short8 z8 = {0, 0, 0, 0, 0, 0, 0, 0};
  short8 x3 = (t >= 3) ? xv[-3 * (NIG / 8)] : z8;
  short8 x2 = (t >= 2) ? xv[-2 * (NIG / 8)] : z8;
  short8 x1 = (t >= 1) ? xv[-1 * (NIG / 8)] : z8;
  short8 x0 = xv[0];
  const float4* cw4 = (const float4*)cw;
  float4 cbl = ((const float4*)cb)[d8 * 2], cbh = ((const float4*)cb)[d8 * 2 + 1];
  float cbv[8] = {cbl.x, cbl.y, cbl.z, cbl.w, cbh.x, cbh.y, cbh.z, cbh.w};
  short8 o;
  #pragma unroll
  for (int j = 0; j < 8; ++j) {
    float4 w = cw4[d0 + j];
    float a = cbv[j];
    a = fmaf(b2f((u16)x3[j]), w.x, a);
    a = fmaf(b2f((u16)x2[j]), w.y, a);
    a = fmaf(b2f((u16)x1[j]), w.z, a);
    a = fmaf(b2f((u16)x0[j]), w.w, a);
    o[j] = (short)f2b(siluf_(a));
  }
  *(short8*)(xab + (size_t)token * DI + d0) = o;
}

// ---------------- chunked selective scan (bf16 state buffers) ----------------
// phase1: local scan from h=0 -> lend bf16[16]; P[c][b][16]=prod(dec)
__global__ __launch_bounds__(256) void scan_phase1(const u16* __restrict__ ub, const float* __restrict__ dec,
                                                   const float* __restrict__ Bm, u16* __restrict__ lend,
                                                   float* __restrict__ P) {
  __shared__ float dl[LCH * NST], bl[LCH * NST];
  int bid = blockIdx.x;
  int dblk = bid % 6, b = (bid / 6) % BATCH, c = bid / (6 * BATCH);
  int d = dblk * 256 + threadIdx.x;
  int t0 = c * LCH;
  size_t base16 = (size_t)(b * SEQ + t0) * NST;
  for (int i = threadIdx.x; i < LCH * NST; i += 256) { dl[i] = dec[base16 + i]; bl[i] = Bm[base16 + i]; }
  __syncthreads();
  float h[NST];
  #pragma unroll
  for (int n = 0; n < NST; ++n) h[n] = 0.f;
  const u16* up = ub + (size_t)(b * SEQ + t0) * DI + d;
  for (int t = 0; t < LCH; ++t) {
    float uu = b2f(up[(size_t)t * DI]);
    #pragma unroll
    for (int n = 0; n < NST; ++n) h[n] = fmaf(h[n], dl[t * NST + n], bl[t * NST + n] * uu);
  }
  u16* lo = lend + ((size_t)(c * BATCH + b) * DI + d) * NST;
  short8 s0, s1;
  #pragma unroll
  for (int n = 0; n < 8; ++n) { s0[n] = (short)f2b(h[n]); s1[n] = (short)f2b(h[8 + n]); }
  ((short8*)lo)[0] = s0;
  ((short8*)lo)[1] = s1;
  if (dblk == 0 && threadIdx.x < NST) {
    float pr = 1.f;
    for (int t = 0; t < LCH; ++t) pr *= dl[t * NST + threadIdx.x];
    P[(size_t)(c * BATCH + b) * NST + threadIdx.x] = pr;
  }
}

// phase2: cross-chunk scan, parallel over (b,d,n); Hin[c] = state entering chunk c (bf16)
__global__ __launch_bounds__(256) void scan_phase2(const u16* __restrict__ lend, const float* __restrict__ P,
                                                   u16* __restrict__ Hin) {
  int flat = blockIdx.x * 256 + threadIdx.x;  // < BATCH*DI*NST
  int n = flat & 15;
  int d = (flat >> 4) % DI;
  int b = flat / (DI * NST);
  float h = 0.f;
  for (int c = 0; c < NCH; ++c) {
    size_t idx = ((size_t)(c * BATCH + b) * DI + d) * NST + n;
    Hin[idx] = f2b(h);
    h = fmaf(P[(size_t)(c * BATCH + b) * NST + n], h, b2f(lend[idx]));
  }
}

// phase3: replay chunk from Hin, emit gy = bf16(silu(gate) * y)
__global__ __launch_bounds__(256) void scan_phase3(const u16* __restrict__ ub, const float* __restrict__ dec,
                                                   const float* __restrict__ Bm, const float* __restrict__ Cm,
                                                   const u16* __restrict__ Hin, const u16* __restrict__ xpg,
                                                   u16* __restrict__ gy) {
  __shared__ float dl[LCH * NST], bl[LCH * NST], cl[LCH * NST];
  int bid = blockIdx.x;
  int dblk = bid % 6, b = (bid / 6) % BATCH, c = bid / (6 * BATCH);
  int d = dblk * 256 + threadIdx.x;
  int t0 = c * LCH;
  size_t base16 = (size_t)(b * SEQ + t0) * NST;
  for (int i = threadIdx.x; i < LCH * NST; i += 256) {
    dl[i] = dec[base16 + i]; bl[i] = Bm[base16 + i]; cl[i] = Cm[base16 + i];
  }
  __syncthreads();
  float h[NST];
  const short8* hi = (const short8*)(Hin + ((size_t)(c * BATCH + b) * DI + d) * NST);
  short8 h0 = hi[0], h1 = hi[1];
  #pragma unroll
  for (int n = 0; n < 8; ++n) { h[n] = b2f((u16)h0[n]); h[8 + n] = b2f((u16)h1[n]); }
  const u16* up = ub + (size_t)(b * SEQ + t0) * DI + d;
  const u16* gp = xpg + (size_t)(b * SEQ + t0) * NIG + DI + d;
  u16* yp = gy + (size_t)(b * SEQ + t0) * DI + d;
  for (int t = 0; t < LCH; ++t) {
    float uu = b2f(up[(size_t)t * DI]);
    float acc = 0.f;
    #pragma unroll
    for (int n = 0; n < NST; ++n) {
      h[n] = fmaf(h[n], dl[t * NST + n], bl[t * NST + n] * uu);
      acc = fmaf(h[n], cl[t * NST + n], acc);
    }
    float g = b2f(gp[(size_t)t * NIG]);
    yp[(size_t)t * DI] = f2b(siluf_(g) * acc);
  }
}

extern "C" void kernel_launch(void* const* d_in, const int* in_sizes, int n_in,
                              void* d_out, int out_size, void* d_ws, size_t ws_size,
                              hipStream_t stream) {
  const float* x      = (const float*)d_in[0];
  const float* ln_g   = (const float*)d_in[1];
  const float* ln_b   = (const float*)d_in[2];
  const float* W_in   = (const float*)d_in[3];
  const float* b_in   = (const float*)d_in[4];
  const float* conv_w = (const float*)d_in[5];
  const float* conv_b = (const float*)d_in[6];
  const float* W_A    = (const float*)d_in[7];
  const float* b_A    = (const float*)d_in[8];
  const float* W_B    = (const float*)d_in[9];
  const float* b_B    = (const float*)d_in[10];
  const float* W_C    = (const float*)d_in[11];
  const float* b_C    = (const float*)d_in[12];
  const float* W_dt   = (const float*)d_in[13];
  const float* b_dt   = (const float*)d_in[14];
  const float* W_S    = (const float*)d_in[15];
  const float* b_S    = (const float*)d_in[16];
  const float* W_gate = (const float*)d_in[17];
  const float* b_gate = (const float*)d_in[18];
  const float* W_out  = (const float*)d_in[19];
  const float* b_out  = (const float*)d_in[20];
  float* out = (float*)d_out;

  char* p = (char*)d_ws;
  auto alloc = [&](size_t bytes) { char* r = p; p += (bytes + 255) & ~(size_t)255; return r; };
  u16*   Wigb    = (u16*)alloc((size_t)NIG * DM * 2);
  float* biasig  = (float*)alloc((size_t)NIG * 4);
  u16*   WSb     = (u16*)alloc((size_t)DI * DI * 2);
  u16*   Woutb   = (u16*)alloc((size_t)DM * DI * 2);
  u16*   Wabcd   = (u16*)alloc((size_t)64 * DI * 2);
  float* bias64  = (float*)alloc(64 * 4);
  u16*   xnb     = (u16*)alloc((size_t)NTOK * DM * 2);
  u16*   xpg     = (u16*)alloc((size_t)NTOK * NIG * 2);
  u16*   xab     = (u16*)alloc((size_t)NTOK * DI * 2);   // reused as gy
  u16*   ub      = (u16*)alloc((size_t)NTOK * DI * 2);
  float* Zp      = (float*)alloc((size_t)4 * NTOK * 64 * 4);
  float* decb    = (float*)alloc((size_t)NTOK * NST * 4);
  float* Bmb     = (float*)alloc((size_t)NTOK * NST * 4);
  float* Cmb     = (float*)alloc((size_t)NTOK * NST * 4);
  u16*   lend    = (u16*)alloc((size_t)NCH * BATCH * DI * NST * 2);
  u16*   Hin     = (u16*)alloc((size_t)NCH * BATCH * DI * NST * 2);
  float* P       = (float*)alloc((size_t)NCH * BATCH * NST * 4);
  u16* gy = xab;

  cast_all<<<(N_CAST + 255) / 256, 256, 0, stream>>>(W_in, W_gate, b_in, b_gate, W_S, W_out,
                                                     W_A, W_dt, W_B, W_C, b_A, b_dt, b_B, b_C,
                                                     Wigb, biasig, WSb, Woutb, Wabcd, bias64);

  ln_kernel<<<NTOK, 256, 0, stream>>>(x, ln_g, ln_b, xnb);

  // fused in|gate GEMM -> xpg bf16
  gemm_bt<2, 128><<<dim3(NIG / 128, NTOK / 128), 512, 0, stream>>>(xnb, Wigb, biasig, nullptr, nullptr,
                                                                   nullptr, xpg, NTOK, NIG, DM);

  conv_silu<<<NTOK * (DI / 8) / 256, 256, 0, stream>>>(xpg, conv_w, conv_b, xab);

  // S GEMM with fused u = xa * sigmoid(Sp) -> ub bf16
  gemm_bt<1, 128><<<dim3(DI / 128, NTOK / 128), 512, 0, stream>>>(xab, WSb, b_S, nullptr, xab,
                                                                  nullptr, ub, NTOK, DI, DI);

  gemm_abcd<<<dim3(NTOK / 64, 4), 256, 0, stream>>>(ub, Wabcd, Zp, NTOK, DI);
  abcd_combine<<<NTOK * 16 / 256, 256, 0, stream>>>(Zp, bias64, decb, Bmb, Cmb, NTOK);

  scan_phase1<<<NCH * BATCH * (DI / 256), 256, 0, stream>>>(ub, decb, Bmb, lend, P);
  scan_phase2<<<BATCH * DI * NST / 256, 256, 0, stream>>>(lend, P, Hin);
  scan_phase3<<<NCH * BATCH * (DI / 256), 256, 0, stream>>>(ub, decb, Bmb, Cmb, Hin, xpg, gy);

  // out GEMM + residual (f32 out): BM=64 -> 384 blocks, all CUs covered
  gemm_bt<0, 64><<<dim3(DM / 128, NTOK / 64), 256, 0, stream>>>(gy, Woutb, b_out, x, nullptr,
                                                                out, nullptr, NTOK, DM, DI);
}